// Round 1
// baseline (3332.503 us; speedup 1.0000x reference)
//
#include <hip/hip_runtime.h>
#include <cmath>

#define Bn 2
#define Sn 2048
#define En 2048
#define Hn 16
#define HDn 128
#define NORMS 64.0f

// ---- sin/cos tables in fp64 (parity with numpy's float64 sin/cos -> f32 cast) ----
static __global__ void rope_table_kernel(float* __restrict__ sinT, float* __restrict__ cosT) {
    int i = blockIdx.x * 256 + threadIdx.x;       // < Sn*64
    int t = i >> 6, f = i & 63;
    double inv = pow(10000.0, -(double)(2 * f) / (double)HDn);
    double ang = (double)t * inv;
    sinT[i] = (float)sin(ang);
    cosT[i] = (float)cos(ang);
}

// ---- fp32 tiled GEMM: C[M][N] = A[M][K] @ W[K][N], 64x64 tile, 4x4/thread ----
static __global__ __launch_bounds__(256) void gemm_nn_kernel(
        const float* __restrict__ A, const float* __restrict__ W, float* __restrict__ C,
        int M, int N, int K) {
    __shared__ float As[16][68];   // As[kk][row], stride 68 keeps 16B alignment
    __shared__ float Bs[16][68];   // Bs[kk][col]
    const int tid = threadIdx.x;
    const int tx = tid & 15, ty = tid >> 4;
    const int row0 = blockIdx.y * 64, col0 = blockIdx.x * 64;
    const int ar = tid >> 2, ac = (tid & 3) * 4;
    const int bk = tid >> 4, bc = (tid & 15) * 4;
    const float* aptr = A + (size_t)(row0 + ar) * K + ac;
    const float* bptr = W + (size_t)bk * N + col0 + bc;
    float acc[4][4] = {};
    for (int k0 = 0; k0 < K; k0 += 16) {
        float4 a4 = *(const float4*)(aptr + k0);
        float4 b4 = *(const float4*)(bptr + (size_t)k0 * N);
        __syncthreads();                       // prev compute done before LDS overwrite
        As[ac+0][ar] = a4.x; As[ac+1][ar] = a4.y; As[ac+2][ar] = a4.z; As[ac+3][ar] = a4.w;
        *(float4*)&Bs[bk][bc] = b4;
        __syncthreads();
        #pragma unroll
        for (int kk = 0; kk < 16; ++kk) {
            float4 av = *(const float4*)&As[kk][ty * 4];
            float4 bv = *(const float4*)&Bs[kk][tx * 4];
            float a_[4] = {av.x, av.y, av.z, av.w};
            float b_[4] = {bv.x, bv.y, bv.z, bv.w};
            #pragma unroll
            for (int i = 0; i < 4; ++i)
                #pragma unroll
                for (int j = 0; j < 4; ++j)
                    acc[i][j] += a_[i] * b_[j];
        }
    }
    #pragma unroll
    for (int i = 0; i < 4; ++i) {
        float4 o = make_float4(acc[i][0], acc[i][1], acc[i][2], acc[i][3]);
        *(float4*)&C[(size_t)(row0 + ty * 4 + i) * N + col0 + tx * 4] = o;
    }
}

// ---- RoPE (note: reference rotates along the SEQUENCE axis) ----
static __global__ void rope_kernel(const float* __restrict__ X, float* __restrict__ Y,
                                   const float* __restrict__ sinT, const float* __restrict__ cosT) {
    int p = blockIdx.x * 256 + threadIdx.x;      // pair index < Bn*Sn*En/2 = 2^22
    int c2 = p & (En / 2 - 1);                   // 0..1023
    int t  = (p >> 10) & (Sn - 1);
    int b  = p >> 21;
    int f  = c2 & 63;                            // (d % 128) / 2
    float sv = sinT[(t << 6) + f], cv = cosT[(t << 6) + f];
    int tsrc; float sgn;
    if (t < Sn / 2) { tsrc = 2 * t + 1; sgn = -1.f; }
    else            { tsrc = 2 * (t - Sn / 2); sgn = 1.f; }
    size_t rowt = ((size_t)b * Sn + t) * En + 2 * c2;
    size_t rows = ((size_t)b * Sn + tsrc) * En + 2 * c2;
    float2 x  = *(const float2*)&X[rowt];
    float2 xs = *(const float2*)&X[rows];
    float2 y;
    y.x = x.x * cv + sgn * xs.x * sv;
    y.y = x.y * cv + sgn * xs.y * sv;
    *(float2*)&Y[rowt] = y;
}

// ---- flash attention: block = (b,h) x 64 q-rows; K/V tiles of 64; online softmax ----
static __global__ __launch_bounds__(256) void flash_kernel(
        const float* __restrict__ Qr, const float* __restrict__ Kr, const float* __restrict__ V,
        const float* __restrict__ mask, float* __restrict__ AO) {
    __shared__ float Qt[HDn][68];       // Q tile transposed [d][row]
    __shared__ float Kt[HDn][68];       // K tile transposed [d][col]
    __shared__ float Vs[64][HDn + 4];   // V tile row-major [j][d]
    __shared__ float Pt[64][68];        // P transposed [j][row]
    __shared__ float red[64][17];       // cross-thread row reductions
    __shared__ float m_s[64], l_s[64], al_s[64], mn_s[64];

    const int tid = threadIdx.x;
    const int tx = tid & 15, ty = tid >> 4;
    const int bh = blockIdx.y;
    const int b = bh >> 4, h = bh & 15;
    const int r0 = blockIdx.x * 64;
    const size_t base = (size_t)b * Sn * En + (size_t)h * HDn;

    #pragma unroll
    for (int it = 0; it < 8; ++it) {    // load Q tile (transposed)
        int i = tid + it * 256;
        int r = i >> 5, c4 = (i & 31) * 4;
        float4 q4 = *(const float4*)&Qr[base + (size_t)(r0 + r) * En + c4];
        Qt[c4 + 0][r] = q4.x; Qt[c4 + 1][r] = q4.y; Qt[c4 + 2][r] = q4.z; Qt[c4 + 3][r] = q4.w;
    }
    if (tid < 64) { m_s[tid] = -INFINITY; l_s[tid] = 0.f; }

    float O[4][8] = {};   // rows ty*4+i; cols tx*4+j (j<4) and 64+tx*4+(j-4)

    for (int j0 = 0; j0 < Sn; j0 += 64) {
        __syncthreads();                 // Q tile visible / prev-iter PV done
        #pragma unroll
        for (int it = 0; it < 8; ++it) { // load K (transposed) + V (row-major)
            int i = tid + it * 256;
            int r = i >> 5, c4 = (i & 31) * 4;
            float4 k4 = *(const float4*)&Kr[base + (size_t)(j0 + r) * En + c4];
            Kt[c4 + 0][r] = k4.x; Kt[c4 + 1][r] = k4.y; Kt[c4 + 2][r] = k4.z; Kt[c4 + 3][r] = k4.w;
            float4 v4 = *(const float4*)&V[base + (size_t)(j0 + r) * En + c4];
            *(float4*)&Vs[r][c4] = v4;
        }
        __syncthreads();

        float sc[4][4] = {};
        #pragma unroll 16
        for (int kk = 0; kk < HDn; ++kk) {
            float4 av = *(const float4*)&Qt[kk][ty * 4];
            float4 bv = *(const float4*)&Kt[kk][tx * 4];
            float a_[4] = {av.x, av.y, av.z, av.w};
            float b_[4] = {bv.x, bv.y, bv.z, bv.w};
            #pragma unroll
            for (int i = 0; i < 4; ++i)
                #pragma unroll
                for (int j = 0; j < 4; ++j)
                    sc[i][j] += a_[i] * b_[j];
        }
        // logits = (qk + mask) * 64 ; partial row max
        #pragma unroll
        for (int i = 0; i < 4; ++i) {
            float rm = -INFINITY;
            #pragma unroll
            for (int j = 0; j < 4; ++j) {
                float mv = mask[(size_t)(r0 + ty * 4 + i) * Sn + (j0 + tx * 4 + j)];
                sc[i][j] = (sc[i][j] + mv) * NORMS;
                rm = fmaxf(rm, sc[i][j]);
            }
            red[ty * 4 + i][tx] = rm;
        }
        __syncthreads();
        if (tid < 64) {                  // online-softmax row stats
            float tm = red[tid][0];
            for (int c = 1; c < 16; ++c) tm = fmaxf(tm, red[tid][c]);
            float mo = m_s[tid];
            float mn = fmaxf(mo, tm);
            mn_s[tid] = mn;
            al_s[tid] = expf(mo - mn);   // first iter: expf(-inf)=0
            m_s[tid] = mn;
        }
        __syncthreads();
        #pragma unroll
        for (int i = 0; i < 4; ++i) {    // exp, store P transposed, partial row sums
            float mn = mn_s[ty * 4 + i];
            float ps = 0.f;
            #pragma unroll
            for (int j = 0; j < 4; ++j) {
                float pe = expf(sc[i][j] - mn);
                ps += pe;
                Pt[tx * 4 + j][ty * 4 + i] = pe;
            }
            red[ty * 4 + i][tx] = ps;
        }
        __syncthreads();
        if (tid < 64) {
            float s = 0.f;
            for (int c = 0; c < 16; ++c) s += red[tid][c];
            l_s[tid] = l_s[tid] * al_s[tid] + s;
        }
        // PV accumulate with rescale
        float al[4];
        #pragma unroll
        for (int i = 0; i < 4; ++i) al[i] = al_s[ty * 4 + i];
        #pragma unroll
        for (int i = 0; i < 4; ++i)
            #pragma unroll
            for (int j = 0; j < 8; ++j) O[i][j] *= al[i];
        #pragma unroll 8
        for (int jj = 0; jj < 64; ++jj) {
            float4 pv = *(const float4*)&Pt[jj][ty * 4];
            float4 v0 = *(const float4*)&Vs[jj][tx * 4];
            float4 v1 = *(const float4*)&Vs[jj][64 + tx * 4];
            float pa[4] = {pv.x, pv.y, pv.z, pv.w};
            float va[8] = {v0.x, v0.y, v0.z, v0.w, v1.x, v1.y, v1.z, v1.w};
            #pragma unroll
            for (int i = 0; i < 4; ++i)
                #pragma unroll
                for (int j = 0; j < 8; ++j)
                    O[i][j] += pa[i] * va[j];
        }
    }
    __syncthreads();
    #pragma unroll
    for (int i = 0; i < 4; ++i) {
        float inv = 1.0f / l_s[ty * 4 + i];
        size_t orow = base + (size_t)(r0 + ty * 4 + i) * En;
        float4 o0 = make_float4(O[i][0] * inv, O[i][1] * inv, O[i][2] * inv, O[i][3] * inv);
        float4 o1 = make_float4(O[i][4] * inv, O[i][5] * inv, O[i][6] * inv, O[i][7] * inv);
        *(float4*)&AO[orow + tx * 4] = o0;
        *(float4*)&AO[orow + 64 + tx * 4] = o1;
    }
}

extern "C" void kernel_launch(void* const* d_in, const int* in_sizes, int n_in,
                              void* d_out, int out_size, void* d_ws, size_t ws_size,
                              hipStream_t stream) {
    const float* inputs = (const float*)d_in[0];
    const float* mask   = (const float*)d_in[1];
    const float* wq     = (const float*)d_in[2];
    const float* wk     = (const float*)d_in[3];
    const float* wv     = (const float*)d_in[4];
    const float* wo     = (const float*)d_in[5];
    float* out = (float*)d_out;
    (void)in_sizes; (void)n_in; (void)out_size; (void)ws_size;

    float* ws = (float*)d_ws;
    const size_t T = (size_t)Bn * Sn * En;       // 8,388,608 floats
    float* Q    = ws;                            // later reused as attention output
    float* K    = ws + T;
    float* V    = ws + 2 * T;
    float* Qr   = ws + 3 * T;
    float* Kr   = ws + 4 * T;
    float* sinT = ws + 5 * T;                    // Sn*64 floats
    float* cosT = sinT + Sn * 64;
    float* AO   = Q;                             // Q dead after rope

    rope_table_kernel<<<(Sn * 64) / 256, 256, 0, stream>>>(sinT, cosT);

    dim3 gg(En / 64, (Bn * Sn) / 64);            // (32, 64)
    gemm_nn_kernel<<<gg, 256, 0, stream>>>(inputs, wq, Q, Bn * Sn, En, En);
    gemm_nn_kernel<<<gg, 256, 0, stream>>>(inputs, wk, K, Bn * Sn, En, En);
    gemm_nn_kernel<<<gg, 256, 0, stream>>>(inputs, wv, V, Bn * Sn, En, En);

    int ropeBlocks = (int)(T / 2 / 256);         // 16384
    rope_kernel<<<ropeBlocks, 256, 0, stream>>>(Q, Qr, sinT, cosT);
    rope_kernel<<<ropeBlocks, 256, 0, stream>>>(K, Kr, sinT, cosT);

    flash_kernel<<<dim3(Sn / 64, Bn * Hn), 256, 0, stream>>>(Qr, Kr, V, mask, AO);

    gemm_nn_kernel<<<gg, 256, 0, stream>>>(AO, wo, out, Bn * Sn, En, En);
}

// Round 2
// 809.856 us; speedup vs baseline: 4.1149x; 4.1149x over previous
//
#include <hip/hip_runtime.h>
#include <hip/hip_bf16.h>
#include <cmath>

#define Bn 2
#define Sn 2048
#define En 2048
#define Hn 16
#define HDn 128
#define Mn (Bn*Sn)
#define NORMS 64.0f

typedef __attribute__((ext_vector_type(8))) short short8;
typedef __attribute__((ext_vector_type(4))) float f32x4;

__device__ __forceinline__ short f2bf(float x) {
    __hip_bfloat16 h = __float2bfloat16(x);
    return *reinterpret_cast<short*>(&h);
}
__device__ __forceinline__ float bf2f(short s) {
    __hip_bfloat16 h = *reinterpret_cast<__hip_bfloat16*>(&s);
    return __bfloat162float(h);
}
__device__ __forceinline__ void gl_lds16(const void* g, void* l) {
    __builtin_amdgcn_global_load_lds(
        (const __attribute__((address_space(1))) unsigned int*)g,
        (__attribute__((address_space(3))) unsigned int*)l, 16, 0, 0);
}

// ---- sin/cos tables in fp64 ----
static __global__ void rope_table_kernel(float* __restrict__ sinT, float* __restrict__ cosT) {
    int i = blockIdx.x * 256 + threadIdx.x;
    int t = i >> 6, f = i & 63;
    double inv = pow(10000.0, -(double)(2 * f) / (double)HDn);
    double ang = (double)t * inv;
    sinT[i] = (float)sin(ang);
    cosT[i] = (float)cos(ang);
}

// ---- split fp32 -> bf16 hi/lo ----
static __global__ void split_x_kernel(const float* __restrict__ X,
                                      short* __restrict__ Xhi, short* __restrict__ Xlo) {
    int i = (blockIdx.x * 256 + threadIdx.x) * 4;
    float4 x = *(const float4*)&X[i];
    short4 hi, lo;
    hi.x = f2bf(x.x); lo.x = f2bf(x.x - bf2f(hi.x));
    hi.y = f2bf(x.y); lo.y = f2bf(x.y - bf2f(hi.y));
    hi.z = f2bf(x.z); lo.z = f2bf(x.z - bf2f(hi.z));
    hi.w = f2bf(x.w); lo.w = f2bf(x.w - bf2f(hi.w));
    *(short4*)&Xhi[i] = hi;
    *(short4*)&Xlo[i] = lo;
}

// ---- transpose W [K][N] fp32 -> WT [N][K] bf16 (hi, optional lo) ----
template<bool SPLIT>
static __global__ __launch_bounds__(256) void wtrans_kernel(const float* __restrict__ W,
        short* __restrict__ Thi, short* __restrict__ Tlo) {
    __shared__ float tile[32][33];
    int tx = threadIdx.x & 31, ty = threadIdx.x >> 5;      // ty 0..7
    int k0 = blockIdx.y * 32, n0 = blockIdx.x * 32;
    #pragma unroll
    for (int i = 0; i < 4; ++i)
        tile[ty + i * 8][tx] = W[(size_t)(k0 + ty + i * 8) * En + n0 + tx];
    __syncthreads();
    #pragma unroll
    for (int i = 0; i < 4; ++i) {
        float v = tile[tx][ty + i * 8];
        size_t idx = (size_t)(n0 + ty + i * 8) * En + k0 + tx;
        short hv = f2bf(v);
        Thi[idx] = hv;
        if (SPLIT) Tlo[idx] = f2bf(v - bf2f(hv));
    }
}

// ---- m97-style MFMA GEMM: C[M][N] = A[M][K] * BT[N][K]^T, 128x128 tile, BK=32 ----
// NPROD=3: A(hi,lo) x B(hi,lo) split products (hi*hi + hi*lo + lo*hi)
// OUTMODE=0: fp32 C row-major; OUTMODE=1: bf16 V^T layout [(b,h,d)][s]
template<int NPROD, int OUTMODE>
static __global__ __launch_bounds__(256) void gemm_kernel(
        const short* __restrict__ Ahi, const short* __restrict__ Alo,
        const short* __restrict__ Bhi, const short* __restrict__ Blo,
        float* __restrict__ Cf, short* __restrict__ Cbt) {
    __shared__ short As_hi[128 * 32];
    __shared__ short Bs_hi[128 * 32];
    __shared__ short As_lo[NPROD == 3 ? 128 * 32 : 8];
    __shared__ short Bs_lo[NPROD == 3 ? 128 * 32 : 8];

    const int tid = threadIdx.x;
    const int w = tid >> 6, l = tid & 63;
    const int quad = l >> 4, l15 = l & 15;
    const int wr = (w >> 1) * 64, wc = (w & 1) * 64;
    const int row0 = blockIdx.y * 128, col0 = blockIdx.x * 128;

    const int off0 = tid * 16;                 // byte offset of chunk0 in 8KB tile
    const int r_a = off0 >> 6;                 // row 0..63 (chunk1 adds 64)
    const int kb = (off0 & 63) >> 1;           // bf16 k offset {0,8,16,24}

    f32x4 acc[4][4];
    #pragma unroll
    for (int i = 0; i < 4; ++i)
        #pragma unroll
        for (int j = 0; j < 4; ++j) acc[i][j] = f32x4{0.f, 0.f, 0.f, 0.f};

    for (int k0 = 0; k0 < En; k0 += 32) {
        const short* ap = Ahi + (size_t)(row0 + r_a) * En + k0 + kb;
        const short* bp = Bhi + (size_t)(col0 + r_a) * En + k0 + kb;
        gl_lds16(ap,           &As_hi[off0 / 2]);
        gl_lds16(ap + 64 * En, &As_hi[(off0 + 4096) / 2]);
        gl_lds16(bp,           &Bs_hi[off0 / 2]);
        gl_lds16(bp + 64 * En, &Bs_hi[(off0 + 4096) / 2]);
        if constexpr (NPROD == 3) {
            const short* ap2 = Alo + (size_t)(row0 + r_a) * En + k0 + kb;
            const short* bp2 = Blo + (size_t)(col0 + r_a) * En + k0 + kb;
            gl_lds16(ap2,           &As_lo[off0 / 2]);
            gl_lds16(ap2 + 64 * En, &As_lo[(off0 + 4096) / 2]);
            gl_lds16(bp2,           &Bs_lo[off0 / 2]);
            gl_lds16(bp2 + 64 * En, &Bs_lo[(off0 + 4096) / 2]);
        }
        __syncthreads();

        short8 bhf[4], blf[4];
        #pragma unroll
        for (int ni = 0; ni < 4; ++ni) {
            bhf[ni] = *(const short8*)&Bs_hi[(wc + ni * 16 + l15) * 32 + quad * 8];
            if constexpr (NPROD == 3)
                blf[ni] = *(const short8*)&Bs_lo[(wc + ni * 16 + l15) * 32 + quad * 8];
        }
        #pragma unroll
        for (int mi = 0; mi < 4; ++mi) {
            short8 ahf = *(const short8*)&As_hi[(wr + mi * 16 + l15) * 32 + quad * 8];
            short8 alf;
            if constexpr (NPROD == 3)
                alf = *(const short8*)&As_lo[(wr + mi * 16 + l15) * 32 + quad * 8];
            #pragma unroll
            for (int ni = 0; ni < 4; ++ni) {
                acc[mi][ni] = __builtin_amdgcn_mfma_f32_16x16x32_bf16(ahf, bhf[ni], acc[mi][ni], 0, 0, 0);
                if constexpr (NPROD == 3) {
                    acc[mi][ni] = __builtin_amdgcn_mfma_f32_16x16x32_bf16(ahf, blf[ni], acc[mi][ni], 0, 0, 0);
                    acc[mi][ni] = __builtin_amdgcn_mfma_f32_16x16x32_bf16(alf, bhf[ni], acc[mi][ni], 0, 0, 0);
                }
            }
        }
        __syncthreads();
    }

    if constexpr (OUTMODE == 0) {
        #pragma unroll
        for (int mi = 0; mi < 4; ++mi)
            #pragma unroll
            for (int ni = 0; ni < 4; ++ni) {
                int r = row0 + wr + mi * 16 + quad * 4;
                int c = col0 + wc + ni * 16 + l15;
                #pragma unroll
                for (int reg = 0; reg < 4; ++reg)
                    Cf[(size_t)(r + reg) * En + c] = acc[mi][ni][reg];
            }
    } else {
        #pragma unroll
        for (int mi = 0; mi < 4; ++mi)
            #pragma unroll
            for (int ni = 0; ni < 4; ++ni) {
                int srow = row0 + wr + mi * 16 + quad * 4;
                int c = col0 + wc + ni * 16 + l15;
                int b = srow >> 11, s = srow & (Sn - 1);
                int h = c >> 7, d = c & 127;
                short4 v;
                v.x = f2bf(acc[mi][ni][0]); v.y = f2bf(acc[mi][ni][1]);
                v.z = f2bf(acc[mi][ni][2]); v.w = f2bf(acc[mi][ni][3]);
                *(short4*)&Cbt[((size_t)(b * Hn + h) * HDn + d) * Sn + s] = v;
            }
    }
}

// ---- RoPE (sequence-axis rotation, as reference) + split to bf16 hi/lo ----
static __global__ void rope_split_kernel(const float* __restrict__ X,
        short* __restrict__ Yhi, short* __restrict__ Ylo,
        const float* __restrict__ sinT, const float* __restrict__ cosT) {
    int p = blockIdx.x * 256 + threadIdx.x;      // pair index < B*S*E/2
    int c2 = p & (En / 2 - 1);
    int t = (p >> 10) & (Sn - 1);
    int bb = p >> 21;
    int f = c2 & 63;
    float sv = sinT[(t << 6) + f], cv = cosT[(t << 6) + f];
    int tsrc; float sgn;
    if (t < Sn / 2) { tsrc = 2 * t + 1; sgn = -1.f; }
    else            { tsrc = 2 * (t - Sn / 2); sgn = 1.f; }
    size_t rowt = ((size_t)bb * Sn + t) * En + 2 * c2;
    size_t rows = ((size_t)bb * Sn + tsrc) * En + 2 * c2;
    float2 x = *(const float2*)&X[rowt];
    float2 xs = *(const float2*)&X[rows];
    float y0 = x.x * cv + sgn * xs.x * sv;
    float y1 = x.y * cv + sgn * xs.y * sv;
    short2 hi, lo;
    hi.x = f2bf(y0); lo.x = f2bf(y0 - bf2f(hi.x));
    hi.y = f2bf(y1); lo.y = f2bf(y1 - bf2f(hi.y));
    *(short2*)&Yhi[rowt] = hi;
    *(short2*)&Ylo[rowt] = lo;
}

// ---- MFMA flash attention ----
// block: 64 q-rows x (b,h); 4 waves, wave w owns 16 q-rows. K/V tiles of 64.
// QK^T: split bf16 (3 products). PV: bf16 P via per-wave LDS bounce, V^T staged.
static __global__ __launch_bounds__(256) void flash2_kernel(
        const short* __restrict__ Qhi, const short* __restrict__ Qlo,
        const short* __restrict__ Khi, const short* __restrict__ Klo,
        const short* __restrict__ Vt, const float* __restrict__ mask,
        short* __restrict__ AO) {
    __shared__ short KH[64 * 128];    // [col][d], 16B-groups XOR-swizzled by (col&7)
    __shared__ short KL[64 * 128];
    __shared__ short VS[128 * 64];    // [d][j],  16B-groups XOR-swizzled by (d&7)
    __shared__ short PS[4][16 * 80];  // per-wave P, row stride 80 bf16 (160 B)

    const int tid = threadIdx.x;
    const int w = tid >> 6, l = tid & 63;
    const int quad = l >> 4, l15 = l & 15;
    const int bh = blockIdx.y, b = bh >> 4, h = bh & 15;
    const int r0 = blockIdx.x * 64;
    const size_t qkbase = (size_t)b * Sn * En + (size_t)h * HDn;

    // ---- stage Q tile into KH/KL, pull A-frags to registers ----
    #pragma unroll
    for (int c = 0; c < 4; ++c) {
        int off = tid * 16 + c * 4096;
        int row = off >> 8;
        int gp = (off >> 4) & 15;
        int gl = gp ^ (row & 7);
        size_t gidx = qkbase + (size_t)(r0 + row) * En + gl * 8;
        gl_lds16(Qhi + gidx, &KH[off / 2]);
        gl_lds16(Qlo + gidx, &KL[off / 2]);
    }
    __syncthreads();
    short8 qh[4], ql[4];
    {
        int row = 16 * w + l15;
        #pragma unroll
        for (int kc = 0; kc < 4; ++kc) {
            int gp = (kc * 4 + quad) ^ (row & 7);
            qh[kc] = *(const short8*)&KH[row * 128 + gp * 8];
            ql[kc] = *(const short8*)&KL[row * 128 + gp * 8];
        }
    }
    __syncthreads();

    f32x4 O[8];
    #pragma unroll
    for (int di = 0; di < 8; ++di) O[di] = f32x4{0.f, 0.f, 0.f, 0.f};
    float m_prev[4] = {-INFINITY, -INFINITY, -INFINITY, -INFINITY};
    float l_run[4] = {0.f, 0.f, 0.f, 0.f};
    const int qrow_base = r0 + 16 * w + quad * 4;

    for (int j0 = 0; j0 < Sn; j0 += 64) {
        // ---- stage K hi/lo and V^T tiles ----
        #pragma unroll
        for (int c = 0; c < 4; ++c) {
            int off = tid * 16 + c * 4096;
            int row = off >> 8;
            int gp = (off >> 4) & 15;
            int gl = gp ^ (row & 7);
            size_t gidx = qkbase + (size_t)(j0 + row) * En + gl * 8;
            gl_lds16(Khi + gidx, &KH[off / 2]);
            gl_lds16(Klo + gidx, &KL[off / 2]);
            int vrow = off >> 7;
            int vgp = (off >> 4) & 7;
            int vgl = vgp ^ (vrow & 7);
            size_t vidx = ((size_t)bh * HDn + vrow) * Sn + j0 + vgl * 8;
            gl_lds16(Vt + vidx, &VS[off / 2]);
        }
        __syncthreads();

        // ---- QK^T (split: 3 products) ----
        f32x4 p[4];
        #pragma unroll
        for (int ni = 0; ni < 4; ++ni) p[ni] = f32x4{0.f, 0.f, 0.f, 0.f};
        #pragma unroll
        for (int ni = 0; ni < 4; ++ni) {
            int col = ni * 16 + l15;
            #pragma unroll
            for (int kc = 0; kc < 4; ++kc) {
                int gp = (kc * 4 + quad) ^ (col & 7);
                short8 kh = *(const short8*)&KH[col * 128 + gp * 8];
                short8 kl = *(const short8*)&KL[col * 128 + gp * 8];
                p[ni] = __builtin_amdgcn_mfma_f32_16x16x32_bf16(qh[kc], kh, p[ni], 0, 0, 0);
                p[ni] = __builtin_amdgcn_mfma_f32_16x16x32_bf16(qh[kc], kl, p[ni], 0, 0, 0);
                p[ni] = __builtin_amdgcn_mfma_f32_16x16x32_bf16(ql[kc], kh, p[ni], 0, 0, 0);
            }
        }

        // ---- online softmax (rows live in 16-lane groups -> shfl reductions) ----
        float sc[4][4], rm[4];
        #pragma unroll
        for (int reg = 0; reg < 4; ++reg) rm[reg] = -INFINITY;
        #pragma unroll
        for (int ni = 0; ni < 4; ++ni)
            #pragma unroll
            for (int reg = 0; reg < 4; ++reg) {
                float mv = mask[(size_t)(qrow_base + reg) * Sn + j0 + ni * 16 + l15];
                float v = (p[ni][reg] + mv) * NORMS;
                sc[ni][reg] = v;
                rm[reg] = fmaxf(rm[reg], v);
            }
        #pragma unroll
        for (int d = 1; d < 16; d <<= 1)
            #pragma unroll
            for (int reg = 0; reg < 4; ++reg)
                rm[reg] = fmaxf(rm[reg], __shfl_xor(rm[reg], d));
        float al[4], mn[4], rs[4];
        #pragma unroll
        for (int reg = 0; reg < 4; ++reg) {
            mn[reg] = fmaxf(m_prev[reg], rm[reg]);
            al[reg] = expf(m_prev[reg] - mn[reg]);
            rs[reg] = 0.f;
        }
        #pragma unroll
        for (int ni = 0; ni < 4; ++ni)
            #pragma unroll
            for (int reg = 0; reg < 4; ++reg) {
                float pe = expf(sc[ni][reg] - mn[reg]);
                rs[reg] += pe;
                PS[w][(quad * 4 + reg) * 80 + ni * 16 + l15] = f2bf(pe);
            }
        #pragma unroll
        for (int d = 1; d < 16; d <<= 1)
            #pragma unroll
            for (int reg = 0; reg < 4; ++reg)
                rs[reg] += __shfl_xor(rs[reg], d);
        #pragma unroll
        for (int reg = 0; reg < 4; ++reg) {
            l_run[reg] = l_run[reg] * al[reg] + rs[reg];
            m_prev[reg] = mn[reg];
        }
        #pragma unroll
        for (int di = 0; di < 8; ++di)
            #pragma unroll
            for (int reg = 0; reg < 4; ++reg)
                O[di][reg] *= al[reg];

        // ---- PV: A = P (per-wave LDS bounce), B = V^T from VS ----
        short8 pa[2];
        #pragma unroll
        for (int kc2 = 0; kc2 < 2; ++kc2)
            pa[kc2] = *(const short8*)&PS[w][l15 * 80 + kc2 * 32 + quad * 8];
        #pragma unroll
        for (int di = 0; di < 8; ++di) {
            int d = di * 16 + l15;
            #pragma unroll
            for (int kc2 = 0; kc2 < 2; ++kc2) {
                int gp = (kc2 * 4 + quad) ^ (d & 7);
                short8 vb = *(const short8*)&VS[d * 64 + gp * 8];
                O[di] = __builtin_amdgcn_mfma_f32_16x16x32_bf16(pa[kc2], vb, O[di], 0, 0, 0);
            }
        }
        __syncthreads();
    }

    // ---- epilogue: O / l -> bf16 AO [b][s][h*128+d] ----
    float inv[4];
    #pragma unroll
    for (int reg = 0; reg < 4; ++reg) inv[reg] = 1.0f / l_run[reg];
    #pragma unroll
    for (int di = 0; di < 8; ++di)
        #pragma unroll
        for (int reg = 0; reg < 4; ++reg) {
            size_t idx = ((size_t)b * Sn + qrow_base + reg) * En + h * HDn + di * 16 + l15;
            AO[idx] = f2bf(O[di][reg] * inv[reg]);
        }
}

extern "C" void kernel_launch(void* const* d_in, const int* in_sizes, int n_in,
                              void* d_out, int out_size, void* d_ws, size_t ws_size,
                              hipStream_t stream) {
    const float* inputs = (const float*)d_in[0];
    const float* mask   = (const float*)d_in[1];
    const float* wq     = (const float*)d_in[2];
    const float* wk     = (const float*)d_in[3];
    const float* wv     = (const float*)d_in[4];
    const float* wo     = (const float*)d_in[5];
    float* out = (float*)d_out;
    (void)in_sizes; (void)n_in; (void)out_size; (void)ws_size;

    char* W8 = (char*)d_ws;
    float* sinT = (float*)(W8 + 0);
    float* cosT = (float*)(W8 + 524288);
    short* Xhi  = (short*)(W8 + 1048576);
    short* Xlo  = (short*)(W8 + 1048576 + 16777216);
    short* WqTh = (short*)(W8 + 34603008);
    short* WqTl = (short*)(W8 + 34603008 + 8388608);
    short* WkTh = (short*)(W8 + 51380224);
    short* WkTl = (short*)(W8 + 51380224 + 8388608);
    short* WvT  = (short*)(W8 + 68157440);
    short* WoT  = (short*)(W8 + 76546048);
    float* Qf   = (float*)(W8 + 84934656);
    float* Kf   = (float*)(W8 + 118489088);
    // aliases (lifetimes disjoint):
    short* Qhi  = WqTh;                               // spans WqTh+WqTl (33.5 MB)
    short* Qlo  = WkTh;                               // spans WkTh+WkTl
    short* Khi  = (short*)(W8 + 84934656);            // over Qf (dead after rope)
    short* Klo  = (short*)(W8 + 84934656 + 16777216);
    short* Vt   = (short*)(W8 + 118489088);           // over Kf (dead after rope)
    short* AO   = (short*)(W8 + 118489088 + 16777216);

    rope_table_kernel<<<512, 256, 0, stream>>>(sinT, cosT);
    split_x_kernel<<<8192, 256, 0, stream>>>(inputs, Xhi, Xlo);
    dim3 tg(64, 64);
    wtrans_kernel<true ><<<tg, 256, 0, stream>>>(wq, WqTh, WqTl);
    wtrans_kernel<true ><<<tg, 256, 0, stream>>>(wk, WkTh, WkTl);
    wtrans_kernel<false><<<tg, 256, 0, stream>>>(wv, WvT, nullptr);
    wtrans_kernel<false><<<tg, 256, 0, stream>>>(wo, WoT, nullptr);

    dim3 gg(En / 128, Mn / 128);   // (16, 32)
    gemm_kernel<3, 0><<<gg, 256, 0, stream>>>(Xhi, Xlo, WqTh, WqTl, Qf, nullptr);
    gemm_kernel<3, 0><<<gg, 256, 0, stream>>>(Xhi, Xlo, WkTh, WkTl, Kf, nullptr);
    rope_split_kernel<<<16384, 256, 0, stream>>>(Qf, Qhi, Qlo, sinT, cosT);
    rope_split_kernel<<<16384, 256, 0, stream>>>(Kf, Khi, Klo, sinT, cosT);
    gemm_kernel<1, 1><<<gg, 256, 0, stream>>>(Xhi, nullptr, WvT, nullptr, nullptr, Vt);

    flash2_kernel<<<dim3(Sn / 64, Bn * Hn), 256, 0, stream>>>(Qhi, Qlo, Khi, Klo, Vt, mask, AO);

    gemm_kernel<1, 0><<<gg, 256, 0, stream>>>(AO, nullptr, WoT, nullptr, out, nullptr);
}

// Round 3
// 788.822 us; speedup vs baseline: 4.2247x; 1.0267x over previous
//
#include <hip/hip_runtime.h>
#include <hip/hip_bf16.h>
#include <cmath>

#define Bn 2
#define Sn 2048
#define En 2048
#define Hn 16
#define HDn 128
#define Mn (Bn*Sn)
#define NORMS2 92.33248261689366f   /* 64 * log2(e) : softmax done in base 2 */

typedef __attribute__((ext_vector_type(8))) short short8;
typedef __attribute__((ext_vector_type(4))) float f32x4;

__device__ __forceinline__ short f2bf(float x) {
    __hip_bfloat16 h = __float2bfloat16(x);
    return *reinterpret_cast<short*>(&h);
}
__device__ __forceinline__ float bf2f(short s) {
    __hip_bfloat16 h = *reinterpret_cast<__hip_bfloat16*>(&s);
    return __bfloat162float(h);
}
__device__ __forceinline__ void gl_lds16(const void* g, void* l) {
    __builtin_amdgcn_global_load_lds(
        (const __attribute__((address_space(1))) unsigned int*)g,
        (__attribute__((address_space(3))) unsigned int*)l, 16, 0, 0);
}

#if __has_builtin(__builtin_amdgcn_exp2f)
#define EXP2(x) __builtin_amdgcn_exp2f(x)
#else
#define EXP2(x) exp2f(x)
#endif

// DPP cross-lane move within 16-lane rows (no LDS pipe).
template<int CTRL>
__device__ __forceinline__ float dppf(float x) {
    int r = __builtin_amdgcn_update_dpp(0, __builtin_bit_cast(int, x), CTRL, 0xf, 0xf, true);
    return __builtin_bit_cast(float, r);
}
// butterfly over 16 lanes with masks {1,2,7,15} == all-DPP
__device__ __forceinline__ float redmax16(float x) {
    x = fmaxf(x, dppf<0xB1>(x));   // quad_perm [1,0,3,2]  xor1
    x = fmaxf(x, dppf<0x4E>(x));   // quad_perm [2,3,0,1]  xor2
    x = fmaxf(x, dppf<0x141>(x));  // row_half_mirror      xor7
    x = fmaxf(x, dppf<0x140>(x));  // row_mirror           xor15
    return x;
}
__device__ __forceinline__ float redsum16(float x) {
    x += dppf<0xB1>(x);
    x += dppf<0x4E>(x);
    x += dppf<0x141>(x);
    x += dppf<0x140>(x);
    return x;
}

// ---- sin/cos tables in fp64 ----
static __global__ void rope_table_kernel(float* __restrict__ sinT, float* __restrict__ cosT) {
    int i = blockIdx.x * 256 + threadIdx.x;
    int t = i >> 6, f = i & 63;
    double inv = pow(10000.0, -(double)(2 * f) / (double)HDn);
    double ang = (double)t * inv;
    sinT[i] = (float)sin(ang);
    cosT[i] = (float)cos(ang);
}

// ---- split fp32 -> bf16 hi/lo ----
static __global__ void split_x_kernel(const float* __restrict__ X,
                                      short* __restrict__ Xhi, short* __restrict__ Xlo) {
    int i = (blockIdx.x * 256 + threadIdx.x) * 4;
    float4 x = *(const float4*)&X[i];
    short4 hi, lo;
    hi.x = f2bf(x.x); lo.x = f2bf(x.x - bf2f(hi.x));
    hi.y = f2bf(x.y); lo.y = f2bf(x.y - bf2f(hi.y));
    hi.z = f2bf(x.z); lo.z = f2bf(x.z - bf2f(hi.z));
    hi.w = f2bf(x.w); lo.w = f2bf(x.w - bf2f(hi.w));
    *(short4*)&Xhi[i] = hi;
    *(short4*)&Xlo[i] = lo;
}

// ---- transpose W [K][N] fp32 -> WT [N][K] bf16 (hi, optional lo) ----
template<bool SPLIT>
static __global__ __launch_bounds__(256) void wtrans_kernel(const float* __restrict__ W,
        short* __restrict__ Thi, short* __restrict__ Tlo) {
    __shared__ float tile[32][33];
    int tx = threadIdx.x & 31, ty = threadIdx.x >> 5;
    int k0 = blockIdx.y * 32, n0 = blockIdx.x * 32;
    #pragma unroll
    for (int i = 0; i < 4; ++i)
        tile[ty + i * 8][tx] = W[(size_t)(k0 + ty + i * 8) * En + n0 + tx];
    __syncthreads();
    #pragma unroll
    for (int i = 0; i < 4; ++i) {
        float v = tile[tx][ty + i * 8];
        size_t idx = (size_t)(n0 + ty + i * 8) * En + k0 + tx;
        short hv = f2bf(v);
        Thi[idx] = hv;
        if (SPLIT) Tlo[idx] = f2bf(v - bf2f(hv));
    }
}

// ---- MFMA GEMM: C[M][N] = A[M][K] * BT[N][K]^T, 128x128 tile, BK=32 ----
// NPROD=3: split products (hi*hi + hi*lo + lo*hi)
// OUTMODE=0: fp32 row-major; 1: bf16 V^T [(b,h,d)][s]; 2: bf16 hi/lo split row-major
template<int NPROD, int OUTMODE>
static __global__ __launch_bounds__(256) void gemm_kernel(
        const short* __restrict__ Ahi, const short* __restrict__ Alo,
        const short* __restrict__ Bhi, const short* __restrict__ Blo,
        float* __restrict__ Cf, short* __restrict__ Cbt, short* __restrict__ Clo) {
    __shared__ short As_hi[128 * 32];
    __shared__ short Bs_hi[128 * 32];
    __shared__ short As_lo[NPROD == 3 ? 128 * 32 : 8];
    __shared__ short Bs_lo[NPROD == 3 ? 128 * 32 : 8];

    const int tid = threadIdx.x;
    const int w = tid >> 6, l = tid & 63;
    const int quad = l >> 4, l15 = l & 15;
    const int wr = (w >> 1) * 64, wc = (w & 1) * 64;
    const int row0 = blockIdx.y * 128, col0 = blockIdx.x * 128;

    const int off0 = tid * 16;
    const int r_a = off0 >> 6;
    const int kb = (off0 & 63) >> 1;

    f32x4 acc[4][4];
    #pragma unroll
    for (int i = 0; i < 4; ++i)
        #pragma unroll
        for (int j = 0; j < 4; ++j) acc[i][j] = f32x4{0.f, 0.f, 0.f, 0.f};

    for (int k0 = 0; k0 < En; k0 += 32) {
        const short* ap = Ahi + (size_t)(row0 + r_a) * En + k0 + kb;
        const short* bp = Bhi + (size_t)(col0 + r_a) * En + k0 + kb;
        gl_lds16(ap,           &As_hi[off0 / 2]);
        gl_lds16(ap + 64 * En, &As_hi[(off0 + 4096) / 2]);
        gl_lds16(bp,           &Bs_hi[off0 / 2]);
        gl_lds16(bp + 64 * En, &Bs_hi[(off0 + 4096) / 2]);
        if constexpr (NPROD == 3) {
            const short* ap2 = Alo + (size_t)(row0 + r_a) * En + k0 + kb;
            const short* bp2 = Blo + (size_t)(col0 + r_a) * En + k0 + kb;
            gl_lds16(ap2,           &As_lo[off0 / 2]);
            gl_lds16(ap2 + 64 * En, &As_lo[(off0 + 4096) / 2]);
            gl_lds16(bp2,           &Bs_lo[off0 / 2]);
            gl_lds16(bp2 + 64 * En, &Bs_lo[(off0 + 4096) / 2]);
        }
        __syncthreads();

        short8 bhf[4], blf[4];
        #pragma unroll
        for (int ni = 0; ni < 4; ++ni) {
            bhf[ni] = *(const short8*)&Bs_hi[(wc + ni * 16 + l15) * 32 + quad * 8];
            if constexpr (NPROD == 3)
                blf[ni] = *(const short8*)&Bs_lo[(wc + ni * 16 + l15) * 32 + quad * 8];
        }
        #pragma unroll
        for (int mi = 0; mi < 4; ++mi) {
            short8 ahf = *(const short8*)&As_hi[(wr + mi * 16 + l15) * 32 + quad * 8];
            short8 alf;
            if constexpr (NPROD == 3)
                alf = *(const short8*)&As_lo[(wr + mi * 16 + l15) * 32 + quad * 8];
            #pragma unroll
            for (int ni = 0; ni < 4; ++ni) {
                acc[mi][ni] = __builtin_amdgcn_mfma_f32_16x16x32_bf16(ahf, bhf[ni], acc[mi][ni], 0, 0, 0);
                if constexpr (NPROD == 3) {
                    acc[mi][ni] = __builtin_amdgcn_mfma_f32_16x16x32_bf16(ahf, blf[ni], acc[mi][ni], 0, 0, 0);
                    acc[mi][ni] = __builtin_amdgcn_mfma_f32_16x16x32_bf16(alf, bhf[ni], acc[mi][ni], 0, 0, 0);
                }
            }
        }
        __syncthreads();
    }

    if constexpr (OUTMODE == 0) {
        #pragma unroll
        for (int mi = 0; mi < 4; ++mi)
            #pragma unroll
            for (int ni = 0; ni < 4; ++ni) {
                int r = row0 + wr + mi * 16 + quad * 4;
                int c = col0 + wc + ni * 16 + l15;
                #pragma unroll
                for (int reg = 0; reg < 4; ++reg)
                    Cf[(size_t)(r + reg) * En + c] = acc[mi][ni][reg];
            }
    } else if constexpr (OUTMODE == 1) {
        #pragma unroll
        for (int mi = 0; mi < 4; ++mi)
            #pragma unroll
            for (int ni = 0; ni < 4; ++ni) {
                int srow = row0 + wr + mi * 16 + quad * 4;
                int c = col0 + wc + ni * 16 + l15;
                int b = srow >> 11, s = srow & (Sn - 1);
                int h = c >> 7, d = c & 127;
                short4 v;
                v.x = f2bf(acc[mi][ni][0]); v.y = f2bf(acc[mi][ni][1]);
                v.z = f2bf(acc[mi][ni][2]); v.w = f2bf(acc[mi][ni][3]);
                *(short4*)&Cbt[((size_t)(b * Hn + h) * HDn + d) * Sn + s] = v;
            }
    } else {
        #pragma unroll
        for (int mi = 0; mi < 4; ++mi)
            #pragma unroll
            for (int ni = 0; ni < 4; ++ni) {
                int r = row0 + wr + mi * 16 + quad * 4;
                int c = col0 + wc + ni * 16 + l15;
                #pragma unroll
                for (int reg = 0; reg < 4; ++reg) {
                    float v = acc[mi][ni][reg];
                    short h = f2bf(v);
                    Cbt[(size_t)(r + reg) * En + c] = h;
                    Clo[(size_t)(r + reg) * En + c] = f2bf(v - bf2f(h));
                }
            }
    }
}

// ---- RoPE on split bf16 hi/lo -> split bf16 hi/lo ----
static __global__ void rope_split2_kernel(const short* __restrict__ Xh, const short* __restrict__ Xl,
        short* __restrict__ Yh, short* __restrict__ Yl,
        const float* __restrict__ sinT, const float* __restrict__ cosT) {
    int p = blockIdx.x * 256 + threadIdx.x;
    int c2 = p & (En / 2 - 1);
    int t = (p >> 10) & (Sn - 1);
    int bb = p >> 21;
    int f = c2 & 63;
    float sv = sinT[(t << 6) + f], cv = cosT[(t << 6) + f];
    int tsrc; float sgn;
    if (t < Sn / 2) { tsrc = 2 * t + 1; sgn = -1.f; }
    else            { tsrc = 2 * (t - Sn / 2); sgn = 1.f; }
    size_t rowt = ((size_t)bb * Sn + t) * En + 2 * c2;
    size_t rows = ((size_t)bb * Sn + tsrc) * En + 2 * c2;
    short2 xh = *(const short2*)&Xh[rowt], xl = *(const short2*)&Xl[rowt];
    short2 sh = *(const short2*)&Xh[rows], sl = *(const short2*)&Xl[rows];
    float x0 = bf2f(xh.x) + bf2f(xl.x), x1 = bf2f(xh.y) + bf2f(xl.y);
    float s0 = bf2f(sh.x) + bf2f(sl.x), s1 = bf2f(sh.y) + bf2f(sl.y);
    float y0 = x0 * cv + sgn * s0 * sv;
    float y1 = x1 * cv + sgn * s1 * sv;
    short2 hi, lo;
    hi.x = f2bf(y0); lo.x = f2bf(y0 - bf2f(hi.x));
    hi.y = f2bf(y1); lo.y = f2bf(y1 - bf2f(hi.y));
    *(short2*)&Yh[rowt] = hi;
    *(short2*)&Yl[rowt] = lo;
}

// ---- MFMA flash attention v3 ----
// 32 KB LDS: [0,8192) = K-hi tile / V tile (phase 2); [8192,16384) = K-lo tile / P scratch.
// 4 blocks/CU. DPP softmax reductions, base-2 exp. 4 barriers/iter.
static __global__ __launch_bounds__(256, 4) void flash3_kernel(
        const short* __restrict__ Qhi, const short* __restrict__ Qlo,
        const short* __restrict__ Khi, const short* __restrict__ Klo,
        const short* __restrict__ Vt, const float* __restrict__ mask,
        short* __restrict__ AO) {
    __shared__ short lds0[16384];

    const int tid = threadIdx.x;
    const int w = tid >> 6, l = tid & 63;
    const int quad = l >> 4, l15 = l & 15;
    const int bh = blockIdx.y, b = bh >> 4, h = bh & 15;
    const int r0 = blockIdx.x * 64;
    const size_t qkbase = (size_t)b * Sn * En + (size_t)h * HDn;
    const int psb = 8192 + w * 1280;      // per-wave P scratch base (in K-lo region)

    // ---- stage Q tile (hi->[0,8K), lo->[8K,16K)), pull A-frags to registers ----
    #pragma unroll
    for (int c = 0; c < 4; ++c) {
        int off = tid * 16 + c * 4096;
        int row = off >> 8;
        int gp = (off >> 4) & 15;
        int gl = gp ^ (row & 7);
        size_t gidx = qkbase + (size_t)(r0 + row) * En + gl * 8;
        gl_lds16(Qhi + gidx, &lds0[off / 2]);
        gl_lds16(Qlo + gidx, &lds0[8192 + off / 2]);
    }
    __syncthreads();
    short8 qh[4], ql[4];
    {
        int row = 16 * w + l15;
        #pragma unroll
        for (int kc = 0; kc < 4; ++kc) {
            int gp = (kc * 4 + quad) ^ (row & 7);
            qh[kc] = *(const short8*)&lds0[row * 128 + gp * 8];
            ql[kc] = *(const short8*)&lds0[8192 + row * 128 + gp * 8];
        }
    }

    f32x4 O[8];
    #pragma unroll
    for (int di = 0; di < 8; ++di) O[di] = f32x4{0.f, 0.f, 0.f, 0.f};
    float m_prev[4] = {-INFINITY, -INFINITY, -INFINITY, -INFINITY};
    float l_run[4] = {0.f, 0.f, 0.f, 0.f};
    const int qrow_base = r0 + 16 * w + quad * 4;

    for (int j0 = 0; j0 < Sn; j0 += 64) {
        __syncthreads();                       // A: prev-iter V/P readers done (+Q frags on iter 0)
        #pragma unroll
        for (int c = 0; c < 4; ++c) {          // stage K hi/lo
            int off = tid * 16 + c * 4096;
            int row = off >> 8;
            int gp = (off >> 4) & 15;
            int gl = gp ^ (row & 7);
            size_t gidx = qkbase + (size_t)(j0 + row) * En + gl * 8;
            gl_lds16(Khi + gidx, &lds0[off / 2]);
            gl_lds16(Klo + gidx, &lds0[8192 + off / 2]);
        }
        __syncthreads();                       // B: K tiles visible

        // ---- QK^T (3 split products) ----
        f32x4 p[4];
        #pragma unroll
        for (int ni = 0; ni < 4; ++ni) p[ni] = f32x4{0.f, 0.f, 0.f, 0.f};
        #pragma unroll
        for (int ni = 0; ni < 4; ++ni) {
            int col = ni * 16 + l15;
            #pragma unroll
            for (int kc = 0; kc < 4; ++kc) {
                int gp = (kc * 4 + quad) ^ (col & 7);
                short8 kh = *(const short8*)&lds0[col * 128 + gp * 8];
                short8 kl = *(const short8*)&lds0[8192 + col * 128 + gp * 8];
                p[ni] = __builtin_amdgcn_mfma_f32_16x16x32_bf16(qh[kc], kh, p[ni], 0, 0, 0);
                p[ni] = __builtin_amdgcn_mfma_f32_16x16x32_bf16(qh[kc], kl, p[ni], 0, 0, 0);
                p[ni] = __builtin_amdgcn_mfma_f32_16x16x32_bf16(ql[kc], kh, p[ni], 0, 0, 0);
            }
        }
        __syncthreads();                       // C: all QK LDS reads done

        #pragma unroll
        for (int c = 0; c < 4; ++c) {          // stage V into [0,8K) region (latency hides under softmax)
            int off = tid * 16 + c * 4096;
            int vrow = off >> 7;
            int vgp = (off >> 4) & 7;
            int vgl = vgp ^ (vrow & 7);
            size_t vidx = ((size_t)bh * HDn + vrow) * Sn + j0 + vgl * 8;
            gl_lds16(Vt + vidx, &lds0[off / 2]);
        }

        // ---- softmax in base 2, DPP reductions ----
        float rm[4] = {-INFINITY, -INFINITY, -INFINITY, -INFINITY};
        #pragma unroll
        for (int ni = 0; ni < 4; ++ni)
            #pragma unroll
            for (int reg = 0; reg < 4; ++reg) {
                float mv = mask[(size_t)(qrow_base + reg) * Sn + j0 + ni * 16 + l15];
                float v = (p[ni][reg] + mv) * NORMS2;
                p[ni][reg] = v;
                rm[reg] = fmaxf(rm[reg], v);
            }
        #pragma unroll
        for (int reg = 0; reg < 4; ++reg) rm[reg] = redmax16(rm[reg]);
        float al[4], mn[4], rs[4];
        #pragma unroll
        for (int reg = 0; reg < 4; ++reg) {
            mn[reg] = fmaxf(m_prev[reg], rm[reg]);
            al[reg] = EXP2(m_prev[reg] - mn[reg]);
            rs[reg] = 0.f;
        }
        #pragma unroll
        for (int ni = 0; ni < 4; ++ni)
            #pragma unroll
            for (int reg = 0; reg < 4; ++reg) {
                float pe = EXP2(p[ni][reg] - mn[reg]);
                rs[reg] += pe;
                // P scratch: row=quad*4+reg, col-group ni stored at (ni^quad) -> conflict-free
                lds0[psb + (quad * 4 + reg) * 80 + ((ni ^ quad) << 4) + l15] = f2bf(pe);
            }
        #pragma unroll
        for (int reg = 0; reg < 4; ++reg) rs[reg] = redsum16(rs[reg]);
        #pragma unroll
        for (int reg = 0; reg < 4; ++reg) {
            l_run[reg] = l_run[reg] * al[reg] + rs[reg];
            m_prev[reg] = mn[reg];
        }
        #pragma unroll
        for (int di = 0; di < 8; ++di)
            #pragma unroll
            for (int reg = 0; reg < 4; ++reg)
                O[di][reg] *= al[reg];

        // P A-frags (own wave's scratch; swizzled group lookup)
        short8 pa[2];
        #pragma unroll
        for (int kc2 = 0; kc2 < 2; ++kc2) {
            int g = kc2 * 2 + (quad >> 1);
            int gs = g ^ (l15 >> 2);
            pa[kc2] = *(const short8*)&lds0[psb + l15 * 80 + (gs << 4) + (quad & 1) * 8];
        }
        __syncthreads();                       // D: V tile visible

        // ---- PV ----
        #pragma unroll
        for (int di = 0; di < 8; ++di) {
            int d = di * 16 + l15;
            #pragma unroll
            for (int kc2 = 0; kc2 < 2; ++kc2) {
                int gp = (kc2 * 4 + quad) ^ (d & 7);
                short8 vb = *(const short8*)&lds0[d * 64 + gp * 8];
                O[di] = __builtin_amdgcn_mfma_f32_16x16x32_bf16(pa[kc2], vb, O[di], 0, 0, 0);
            }
        }
    }

    // ---- epilogue ----
    float inv[4];
    #pragma unroll
    for (int reg = 0; reg < 4; ++reg) inv[reg] = 1.0f / l_run[reg];
    #pragma unroll
    for (int di = 0; di < 8; ++di)
        #pragma unroll
        for (int reg = 0; reg < 4; ++reg) {
            size_t idx = ((size_t)b * Sn + qrow_base + reg) * En + h * HDn + di * 16 + l15;
            AO[idx] = f2bf(O[di][reg] * inv[reg]);
        }
}

extern "C" void kernel_launch(void* const* d_in, const int* in_sizes, int n_in,
                              void* d_out, int out_size, void* d_ws, size_t ws_size,
                              hipStream_t stream) {
    const float* inputs = (const float*)d_in[0];
    const float* mask   = (const float*)d_in[1];
    const float* wq     = (const float*)d_in[2];
    const float* wk     = (const float*)d_in[3];
    const float* wv     = (const float*)d_in[4];
    const float* wo     = (const float*)d_in[5];
    float* out = (float*)d_out;
    (void)in_sizes; (void)n_in; (void)out_size; (void)ws_size;

    char* W8 = (char*)d_ws;
    float* sinT = (float*)(W8 + 0);
    float* cosT = (float*)(W8 + 524288);
    short* Xhi  = (short*)(W8 + 1048576);
    short* Xlo  = (short*)(W8 + 17825792);
    short* WqTh = (short*)(W8 + 34603008);
    short* WqTl = (short*)(W8 + 42991616);
    short* WkTh = (short*)(W8 + 51380224);
    short* WkTl = (short*)(W8 + 59768832);
    short* WvT  = (short*)(W8 + 68157440);
    short* WoT  = (short*)(W8 + 76546048);
    short* Qpre_hi = (short*)(W8 + 84934656);
    short* Qpre_lo = (short*)(W8 + 101711872);
    short* Kpre_hi = (short*)(W8 + 118489088);
    short* Kpre_lo = (short*)(W8 + 135266304);
    // aliases (lifetimes disjoint; ordering enforced by dispatch sequence):
    short* Qhi = WqTh;                         // rope-Q out over Wq (dead after K-proj)
    short* Qlo = WkTh;                         // over Wk
    short* Khi = Qpre_hi;                      // rope-K out over Q-pre (dead after rope-Q)
    short* Klo = Qpre_lo;
    short* Vt  = Kpre_hi;                      // V^T over K-pre (dead after rope-K)
    short* AO  = Xhi;                          // flash out over X-hi (dead after V-gemm)

    rope_table_kernel<<<512, 256, 0, stream>>>(sinT, cosT);
    split_x_kernel<<<8192, 256, 0, stream>>>(inputs, Xhi, Xlo);
    dim3 tg(64, 64);
    wtrans_kernel<true ><<<tg, 256, 0, stream>>>(wq, WqTh, WqTl);
    wtrans_kernel<true ><<<tg, 256, 0, stream>>>(wk, WkTh, WkTl);
    wtrans_kernel<false><<<tg, 256, 0, stream>>>(wv, WvT, nullptr);
    wtrans_kernel<false><<<tg, 256, 0, stream>>>(wo, WoT, nullptr);

    dim3 gg(En / 128, Mn / 128);   // (16, 32)
    gemm_kernel<3, 2><<<gg, 256, 0, stream>>>(Xhi, Xlo, WqTh, WqTl, nullptr, Qpre_hi, Qpre_lo);
    gemm_kernel<3, 2><<<gg, 256, 0, stream>>>(Xhi, Xlo, WkTh, WkTl, nullptr, Kpre_hi, Kpre_lo);
    rope_split2_kernel<<<16384, 256, 0, stream>>>(Qpre_hi, Qpre_lo, Qhi, Qlo, sinT, cosT);
    rope_split2_kernel<<<16384, 256, 0, stream>>>(Kpre_hi, Kpre_lo, Khi, Klo, sinT, cosT);
    gemm_kernel<1, 1><<<gg, 256, 0, stream>>>(Xhi, nullptr, WvT, nullptr, nullptr, Vt, nullptr);

    flash3_kernel<<<dim3(Sn / 64, Bn * Hn), 256, 0, stream>>>(Qhi, Qlo, Khi, Klo, Vt, mask, AO);

    gemm_kernel<1, 0><<<gg, 256, 0, stream>>>(AO, nullptr, WoT, nullptr, out, nullptr, nullptr);
}

// Round 4
// 766.572 us; speedup vs baseline: 4.3473x; 1.0290x over previous
//
#include <hip/hip_runtime.h>
#include <hip/hip_bf16.h>
#include <cmath>

#define Bn 2
#define Sn 2048
#define En 2048
#define Hn 16
#define HDn 128
#define Mn (Bn*Sn)
#define NORMS2 92.33248261689366f   /* 64 * log2(e) : softmax done in base 2 */

typedef __attribute__((ext_vector_type(8))) short short8;
typedef __attribute__((ext_vector_type(4))) float f32x4;

__device__ __forceinline__ short f2bf(float x) {
    __hip_bfloat16 h = __float2bfloat16(x);
    return *reinterpret_cast<short*>(&h);
}
__device__ __forceinline__ float bf2f(short s) {
    __hip_bfloat16 h = *reinterpret_cast<__hip_bfloat16*>(&s);
    return __bfloat162float(h);
}
__device__ __forceinline__ void gl_lds16(const void* g, void* l) {
    __builtin_amdgcn_global_load_lds(
        (const __attribute__((address_space(1))) unsigned int*)g,
        (__attribute__((address_space(3))) unsigned int*)l, 16, 0, 0);
}

#if __has_builtin(__builtin_amdgcn_exp2f)
#define EXP2(x) __builtin_amdgcn_exp2f(x)
#else
#define EXP2(x) exp2f(x)
#endif

// DPP cross-lane move within 16-lane rows (no LDS pipe).
template<int CTRL>
__device__ __forceinline__ float dppf(float x) {
    int r = __builtin_amdgcn_update_dpp(0, __builtin_bit_cast(int, x), CTRL, 0xf, 0xf, true);
    return __builtin_bit_cast(float, r);
}
__device__ __forceinline__ float redmax16(float x) {
    x = fmaxf(x, dppf<0xB1>(x));   // quad_perm xor1
    x = fmaxf(x, dppf<0x4E>(x));   // quad_perm xor2
    x = fmaxf(x, dppf<0x141>(x));  // row_half_mirror xor7
    x = fmaxf(x, dppf<0x140>(x));  // row_mirror xor15
    return x;
}
__device__ __forceinline__ float redsum16(float x) {
    x += dppf<0xB1>(x);
    x += dppf<0x4E>(x);
    x += dppf<0x141>(x);
    x += dppf<0x140>(x);
    return x;
}

// ---- sin/cos tables in fp64 ----
static __global__ void rope_table_kernel(float* __restrict__ sinT, float* __restrict__ cosT) {
    int i = blockIdx.x * 256 + threadIdx.x;
    int t = i >> 6, f = i & 63;
    double inv = pow(10000.0, -(double)(2 * f) / (double)HDn);
    double ang = (double)t * inv;
    sinT[i] = (float)sin(ang);
    cosT[i] = (float)cos(ang);
}

// ---- split fp32 -> bf16 hi/lo ----
static __global__ void split_x_kernel(const float* __restrict__ X,
                                      short* __restrict__ Xhi, short* __restrict__ Xlo) {
    int i = (blockIdx.x * 256 + threadIdx.x) * 4;
    float4 x = *(const float4*)&X[i];
    short4 hi, lo;
    hi.x = f2bf(x.x); lo.x = f2bf(x.x - bf2f(hi.x));
    hi.y = f2bf(x.y); lo.y = f2bf(x.y - bf2f(hi.y));
    hi.z = f2bf(x.z); lo.z = f2bf(x.z - bf2f(hi.z));
    hi.w = f2bf(x.w); lo.w = f2bf(x.w - bf2f(hi.w));
    *(short4*)&Xhi[i] = hi;
    *(short4*)&Xlo[i] = lo;
}

// ---- transpose W [K][N] fp32 -> WT [N][K] bf16 (hi, optional lo) ----
template<bool SPLIT>
static __global__ __launch_bounds__(256) void wtrans_kernel(const float* __restrict__ W,
        short* __restrict__ Thi, short* __restrict__ Tlo) {
    __shared__ float tile[32][33];
    int tx = threadIdx.x & 31, ty = threadIdx.x >> 5;
    int k0 = blockIdx.y * 32, n0 = blockIdx.x * 32;
    #pragma unroll
    for (int i = 0; i < 4; ++i)
        tile[ty + i * 8][tx] = W[(size_t)(k0 + ty + i * 8) * En + n0 + tx];
    __syncthreads();
    #pragma unroll
    for (int i = 0; i < 4; ++i) {
        float v = tile[tx][ty + i * 8];
        size_t idx = (size_t)(n0 + ty + i * 8) * En + k0 + tx;
        short hv = f2bf(v);
        Thi[idx] = hv;
        if (SPLIT) Tlo[idx] = f2bf(v - bf2f(hv));
    }
}

// ---- MFMA GEMM: C[M][N] = A[M][K] * BT[N][K]^T, 128x128 tile, BK=32 ----
template<int NPROD, int OUTMODE>
static __global__ __launch_bounds__(256) void gemm_kernel(
        const short* __restrict__ Ahi, const short* __restrict__ Alo,
        const short* __restrict__ Bhi, const short* __restrict__ Blo,
        float* __restrict__ Cf, short* __restrict__ Cbt, short* __restrict__ Clo) {
    __shared__ short As_hi[128 * 32];
    __shared__ short Bs_hi[128 * 32];
    __shared__ short As_lo[NPROD == 3 ? 128 * 32 : 8];
    __shared__ short Bs_lo[NPROD == 3 ? 128 * 32 : 8];

    const int tid = threadIdx.x;
    const int w = tid >> 6, l = tid & 63;
    const int quad = l >> 4, l15 = l & 15;
    const int wr = (w >> 1) * 64, wc = (w & 1) * 64;
    const int row0 = blockIdx.y * 128, col0 = blockIdx.x * 128;

    const int off0 = tid * 16;
    const int r_a = off0 >> 6;
    const int kb = (off0 & 63) >> 1;

    f32x4 acc[4][4];
    #pragma unroll
    for (int i = 0; i < 4; ++i)
        #pragma unroll
        for (int j = 0; j < 4; ++j) acc[i][j] = f32x4{0.f, 0.f, 0.f, 0.f};

    for (int k0 = 0; k0 < En; k0 += 32) {
        const short* ap = Ahi + (size_t)(row0 + r_a) * En + k0 + kb;
        const short* bp = Bhi + (size_t)(col0 + r_a) * En + k0 + kb;
        gl_lds16(ap,           &As_hi[off0 / 2]);
        gl_lds16(ap + 64 * En, &As_hi[(off0 + 4096) / 2]);
        gl_lds16(bp,           &Bs_hi[off0 / 2]);
        gl_lds16(bp + 64 * En, &Bs_hi[(off0 + 4096) / 2]);
        if constexpr (NPROD == 3) {
            const short* ap2 = Alo + (size_t)(row0 + r_a) * En + k0 + kb;
            const short* bp2 = Blo + (size_t)(col0 + r_a) * En + k0 + kb;
            gl_lds16(ap2,           &As_lo[off0 / 2]);
            gl_lds16(ap2 + 64 * En, &As_lo[(off0 + 4096) / 2]);
            gl_lds16(bp2,           &Bs_lo[off0 / 2]);
            gl_lds16(bp2 + 64 * En, &Bs_lo[(off0 + 4096) / 2]);
        }
        __syncthreads();

        short8 bhf[4], blf[4];
        #pragma unroll
        for (int ni = 0; ni < 4; ++ni) {
            bhf[ni] = *(const short8*)&Bs_hi[(wc + ni * 16 + l15) * 32 + quad * 8];
            if constexpr (NPROD == 3)
                blf[ni] = *(const short8*)&Bs_lo[(wc + ni * 16 + l15) * 32 + quad * 8];
        }
        #pragma unroll
        for (int mi = 0; mi < 4; ++mi) {
            short8 ahf = *(const short8*)&As_hi[(wr + mi * 16 + l15) * 32 + quad * 8];
            short8 alf;
            if constexpr (NPROD == 3)
                alf = *(const short8*)&As_lo[(wr + mi * 16 + l15) * 32 + quad * 8];
            #pragma unroll
            for (int ni = 0; ni < 4; ++ni) {
                acc[mi][ni] = __builtin_amdgcn_mfma_f32_16x16x32_bf16(ahf, bhf[ni], acc[mi][ni], 0, 0, 0);
                if constexpr (NPROD == 3) {
                    acc[mi][ni] = __builtin_amdgcn_mfma_f32_16x16x32_bf16(ahf, blf[ni], acc[mi][ni], 0, 0, 0);
                    acc[mi][ni] = __builtin_amdgcn_mfma_f32_16x16x32_bf16(alf, bhf[ni], acc[mi][ni], 0, 0, 0);
                }
            }
        }
        __syncthreads();
    }

    if constexpr (OUTMODE == 0) {
        #pragma unroll
        for (int mi = 0; mi < 4; ++mi)
            #pragma unroll
            for (int ni = 0; ni < 4; ++ni) {
                int r = row0 + wr + mi * 16 + quad * 4;
                int c = col0 + wc + ni * 16 + l15;
                #pragma unroll
                for (int reg = 0; reg < 4; ++reg)
                    Cf[(size_t)(r + reg) * En + c] = acc[mi][ni][reg];
            }
    } else if constexpr (OUTMODE == 1) {
        #pragma unroll
        for (int mi = 0; mi < 4; ++mi)
            #pragma unroll
            for (int ni = 0; ni < 4; ++ni) {
                int srow = row0 + wr + mi * 16 + quad * 4;
                int c = col0 + wc + ni * 16 + l15;
                int b = srow >> 11, s = srow & (Sn - 1);
                int h = c >> 7, d = c & 127;
                short4 v;
                v.x = f2bf(acc[mi][ni][0]); v.y = f2bf(acc[mi][ni][1]);
                v.z = f2bf(acc[mi][ni][2]); v.w = f2bf(acc[mi][ni][3]);
                *(short4*)&Cbt[((size_t)(b * Hn + h) * HDn + d) * Sn + s] = v;
            }
    } else {
        #pragma unroll
        for (int mi = 0; mi < 4; ++mi)
            #pragma unroll
            for (int ni = 0; ni < 4; ++ni) {
                int r = row0 + wr + mi * 16 + quad * 4;
                int c = col0 + wc + ni * 16 + l15;
                #pragma unroll
                for (int reg = 0; reg < 4; ++reg) {
                    float v = acc[mi][ni][reg];
                    short h = f2bf(v);
                    Cbt[(size_t)(r + reg) * En + c] = h;
                    Clo[(size_t)(r + reg) * En + c] = f2bf(v - bf2f(h));
                }
            }
    }
}

// ---- RoPE on split bf16 (Q and K merged into one dispatch via high bit) ----
static __global__ void rope_split2_kernel(
        const short* __restrict__ QXh, const short* __restrict__ QXl,
        short* __restrict__ QYh, short* __restrict__ QYl,
        const short* __restrict__ KXh, const short* __restrict__ KXl,
        short* __restrict__ KYh, short* __restrict__ KYl,
        const float* __restrict__ sinT, const float* __restrict__ cosT) {
    int p = blockIdx.x * 256 + threadIdx.x;
    int sel = p >> 22;                    // 0 = Q, 1 = K (wave-uniform)
    p &= (1 << 22) - 1;
    const short* Xh = sel ? KXh : QXh;
    const short* Xl = sel ? KXl : QXl;
    short* Yh = sel ? KYh : QYh;
    short* Yl = sel ? KYl : QYl;
    int c2 = p & (En / 2 - 1);
    int t = (p >> 10) & (Sn - 1);
    int bb = p >> 21;
    int f = c2 & 63;
    float sv = sinT[(t << 6) + f], cv = cosT[(t << 6) + f];
    int tsrc; float sgn;
    if (t < Sn / 2) { tsrc = 2 * t + 1; sgn = -1.f; }
    else            { tsrc = 2 * (t - Sn / 2); sgn = 1.f; }
    size_t rowt = ((size_t)bb * Sn + t) * En + 2 * c2;
    size_t rows = ((size_t)bb * Sn + tsrc) * En + 2 * c2;
    short2 xh = *(const short2*)&Xh[rowt], xl = *(const short2*)&Xl[rowt];
    short2 sh = *(const short2*)&Xh[rows], sl = *(const short2*)&Xl[rows];
    float x0 = bf2f(xh.x) + bf2f(xl.x), x1 = bf2f(xh.y) + bf2f(xl.y);
    float s0 = bf2f(sh.x) + bf2f(sl.x), s1 = bf2f(sh.y) + bf2f(sl.y);
    float y0 = x0 * cv + sgn * s0 * sv;
    float y1 = x1 * cv + sgn * s1 * sv;
    short2 hi, lo;
    hi.x = f2bf(y0); lo.x = f2bf(y0 - bf2f(hi.x));
    hi.y = f2bf(y1); lo.y = f2bf(y1 - bf2f(hi.y));
    *(short2*)&Yh[rowt] = hi;
    *(short2*)&Yl[rowt] = lo;
}

// ---- MFMA flash attention v4 ----
// 512 threads (8 waves), 128 q-rows/block, 64-key tiles.
// LDS (shorts): [0,8192)=K-hi  [8192,16384)=K-lo  [16384,24576)=V  [24576,34816)=P
// 2 barriers/iter; K+V staged together; mask prefetched to regs; XCD-swizzled grid.
static __global__ __launch_bounds__(512, 4) void flash4_kernel(
        const short* __restrict__ Qhi, const short* __restrict__ Qlo,
        const short* __restrict__ Khi, const short* __restrict__ Klo,
        const short* __restrict__ Vt, const float* __restrict__ mask,
        short* __restrict__ AO) {
    __shared__ short lds0[34816];

    const int tid = threadIdx.x;
    const int w = tid >> 6, l = tid & 63;
    const int quad = l >> 4, l15 = l & 15;
    // XCD-aware decode: all 16 q-tiles of a head land on one XCD (round-robin heuristic)
    const int n = blockIdx.x;
    const int bh = (n & 7) * 4 + ((n >> 3) & 3);
    const int qt = n >> 5;
    const int b = bh >> 4, h = bh & 15;
    const int r0 = qt * 128;
    const size_t qkbase = (size_t)b * Sn * En + (size_t)h * HDn;
    const int psb = 24576 + w * 1280;

    // ---- stage Q tile: hi -> [0,16384), lo -> [16384,32768) ----
    #pragma unroll
    for (int c = 0; c < 4; ++c) {
        int off = tid * 16 + c * 8192;       // [0,32768) bytes
        int row = off >> 8;
        int gp = (off >> 4) & 15;
        int gl = gp ^ (row & 7);
        size_t gidx = qkbase + (size_t)(r0 + row) * En + gl * 8;
        gl_lds16(Qhi + gidx, &lds0[off / 2]);
        gl_lds16(Qlo + gidx, &lds0[16384 + off / 2]);
    }
    __syncthreads();
    short8 qh[4], ql[4];
    {
        int row = 16 * w + l15;
        #pragma unroll
        for (int kc = 0; kc < 4; ++kc) {
            int gp = (kc * 4 + quad) ^ (row & 7);
            qh[kc] = *(const short8*)&lds0[row * 128 + gp * 8];
            ql[kc] = *(const short8*)&lds0[16384 + row * 128 + gp * 8];
        }
    }

    f32x4 O[8];
    #pragma unroll
    for (int di = 0; di < 8; ++di) O[di] = f32x4{0.f, 0.f, 0.f, 0.f};
    float m_prev[4] = {-INFINITY, -INFINITY, -INFINITY, -INFINITY};
    float l_run[4] = {0.f, 0.f, 0.f, 0.f};
    const int qrow_base = r0 + 16 * w + quad * 4;

    for (int j0 = 0; j0 < Sn; j0 += 64) {
        __syncthreads();                       // A: all waves done reading prev K/V (+Q frags)
        #pragma unroll
        for (int c = 0; c < 2; ++c) {          // stage K hi/lo (16 KB each)
            int off = tid * 16 + c * 8192;     // [0,16384)
            int row = off >> 8;
            int gp = (off >> 4) & 15;
            int gl = gp ^ (row & 7);
            size_t gidx = qkbase + (size_t)(j0 + row) * En + gl * 8;
            gl_lds16(Khi + gidx, &lds0[off / 2]);
            gl_lds16(Klo + gidx, &lds0[8192 + off / 2]);
        }
        #pragma unroll
        for (int c = 0; c < 2; ++c) {          // stage V (16 KB)
            int off = tid * 16 + c * 8192;     // [0,16384) bytes of V region
            int vrow = off >> 7;
            int vgp = (off >> 4) & 7;
            int vgl = vgp ^ (vrow & 7);
            size_t vidx = ((size_t)bh * HDn + vrow) * Sn + j0 + vgl * 8;
            gl_lds16(Vt + vidx, &lds0[16384 + off / 2]);
        }
        float mv[4][4];                        // mask prefetch (latency shares the barrier drain)
        #pragma unroll
        for (int ni = 0; ni < 4; ++ni)
            #pragma unroll
            for (int reg = 0; reg < 4; ++reg)
                mv[ni][reg] = mask[(size_t)(qrow_base + reg) * Sn + j0 + ni * 16 + l15];
        __syncthreads();                       // B: K/V visible (implicit vmcnt(0))

        // ---- QK^T (3 split products) ----
        f32x4 p[4];
        #pragma unroll
        for (int ni = 0; ni < 4; ++ni) p[ni] = f32x4{0.f, 0.f, 0.f, 0.f};
        #pragma unroll
        for (int ni = 0; ni < 4; ++ni) {
            int col = ni * 16 + l15;
            #pragma unroll
            for (int kc = 0; kc < 4; ++kc) {
                int gp = (kc * 4 + quad) ^ (col & 7);
                short8 kh = *(const short8*)&lds0[col * 128 + gp * 8];
                short8 kl = *(const short8*)&lds0[8192 + col * 128 + gp * 8];
                p[ni] = __builtin_amdgcn_mfma_f32_16x16x32_bf16(qh[kc], kh, p[ni], 0, 0, 0);
                p[ni] = __builtin_amdgcn_mfma_f32_16x16x32_bf16(qh[kc], kl, p[ni], 0, 0, 0);
                p[ni] = __builtin_amdgcn_mfma_f32_16x16x32_bf16(ql[kc], kh, p[ni], 0, 0, 0);
            }
        }

        // ---- softmax in base 2, DPP reductions ----
        float rm[4] = {-INFINITY, -INFINITY, -INFINITY, -INFINITY};
        #pragma unroll
        for (int ni = 0; ni < 4; ++ni)
            #pragma unroll
            for (int reg = 0; reg < 4; ++reg) {
                float v = (p[ni][reg] + mv[ni][reg]) * NORMS2;
                p[ni][reg] = v;
                rm[reg] = fmaxf(rm[reg], v);
            }
        #pragma unroll
        for (int reg = 0; reg < 4; ++reg) rm[reg] = redmax16(rm[reg]);
        float al[4], mn[4], rs[4];
        #pragma unroll
        for (int reg = 0; reg < 4; ++reg) {
            mn[reg] = fmaxf(m_prev[reg], rm[reg]);
            al[reg] = EXP2(m_prev[reg] - mn[reg]);
            rs[reg] = 0.f;
        }
        #pragma unroll
        for (int ni = 0; ni < 4; ++ni)
            #pragma unroll
            for (int reg = 0; reg < 4; ++reg) {
                float pe = EXP2(p[ni][reg] - mn[reg]);
                rs[reg] += pe;
                lds0[psb + (quad * 4 + reg) * 80 + ((ni ^ quad) << 4) + l15] = f2bf(pe);
            }
        #pragma unroll
        for (int reg = 0; reg < 4; ++reg) rs[reg] = redsum16(rs[reg]);
        #pragma unroll
        for (int reg = 0; reg < 4; ++reg) {
            l_run[reg] = l_run[reg] * al[reg] + rs[reg];
            m_prev[reg] = mn[reg];
        }
        #pragma unroll
        for (int di = 0; di < 8; ++di)
            #pragma unroll
            for (int reg = 0; reg < 4; ++reg)
                O[di][reg] *= al[reg];

        // ---- P A-frags (same-wave LDS round-trip, no barrier) ----
        short8 pa[2];
        #pragma unroll
        for (int kc2 = 0; kc2 < 2; ++kc2) {
            int g = kc2 * 2 + (quad >> 1);
            int gs = g ^ (l15 >> 2);
            pa[kc2] = *(const short8*)&lds0[psb + l15 * 80 + (gs << 4) + (quad & 1) * 8];
        }

        // ---- PV ----
        #pragma unroll
        for (int di = 0; di < 8; ++di) {
            int d = di * 16 + l15;
            #pragma unroll
            for (int kc2 = 0; kc2 < 2; ++kc2) {
                int gp = (kc2 * 4 + quad) ^ (d & 7);
                short8 vb = *(const short8*)&lds0[16384 + d * 64 + gp * 8];
                O[di] = __builtin_amdgcn_mfma_f32_16x16x32_bf16(pa[kc2], vb, O[di], 0, 0, 0);
            }
        }
    }

    // ---- epilogue ----
    float inv[4];
    #pragma unroll
    for (int reg = 0; reg < 4; ++reg) inv[reg] = 1.0f / l_run[reg];
    #pragma unroll
    for (int di = 0; di < 8; ++di)
        #pragma unroll
        for (int reg = 0; reg < 4; ++reg) {
            size_t idx = ((size_t)b * Sn + qrow_base + reg) * En + h * HDn + di * 16 + l15;
            AO[idx] = f2bf(O[di][reg] * inv[reg]);
        }
}

extern "C" void kernel_launch(void* const* d_in, const int* in_sizes, int n_in,
                              void* d_out, int out_size, void* d_ws, size_t ws_size,
                              hipStream_t stream) {
    const float* inputs = (const float*)d_in[0];
    const float* mask   = (const float*)d_in[1];
    const float* wq     = (const float*)d_in[2];
    const float* wk     = (const float*)d_in[3];
    const float* wv     = (const float*)d_in[4];
    const float* wo     = (const float*)d_in[5];
    float* out = (float*)d_out;
    (void)in_sizes; (void)n_in; (void)out_size; (void)ws_size;

    char* W8 = (char*)d_ws;
    float* sinT = (float*)(W8 + 0);
    float* cosT = (float*)(W8 + 524288);
    short* Xhi  = (short*)(W8 + 1048576);
    short* Xlo  = (short*)(W8 + 17825792);
    short* WqTh = (short*)(W8 + 34603008);
    short* WqTl = (short*)(W8 + 42991616);
    short* WkTh = (short*)(W8 + 51380224);
    short* WkTl = (short*)(W8 + 59768832);
    short* WvT  = (short*)(W8 + 68157440);
    short* WoT  = (short*)(W8 + 76546048);
    short* Qpre_hi = (short*)(W8 + 84934656);
    short* Qpre_lo = (short*)(W8 + 101711872);
    short* Kpre_hi = (short*)(W8 + 118489088);
    short* Kpre_lo = (short*)(W8 + 135266304);
    // aliases (lifetimes disjoint; ordering enforced by dispatch sequence):
    short* Qhi = WqTh;                         // rope-Q out over Wq (dead after K-proj)
    short* Qlo = WkTh;                         // over Wk
    short* Khi = (short*)(W8 + 152043520);     // fresh region (rope merged: can't overlay Qpre)
    short* Klo = (short*)(W8 + 168820736);
    short* Vt  = Kpre_hi;                      // V^T over K-pre (dead after rope)
    short* AO  = Xhi;                          // flash out over X-hi (dead after V-gemm)

    rope_table_kernel<<<512, 256, 0, stream>>>(sinT, cosT);
    split_x_kernel<<<8192, 256, 0, stream>>>(inputs, Xhi, Xlo);
    dim3 tg(64, 64);
    wtrans_kernel<true ><<<tg, 256, 0, stream>>>(wq, WqTh, WqTl);
    wtrans_kernel<true ><<<tg, 256, 0, stream>>>(wk, WkTh, WkTl);
    wtrans_kernel<false><<<tg, 256, 0, stream>>>(wv, WvT, nullptr);
    wtrans_kernel<false><<<tg, 256, 0, stream>>>(wo, WoT, nullptr);

    dim3 gg(En / 128, Mn / 128);   // (16, 32)
    gemm_kernel<3, 2><<<gg, 256, 0, stream>>>(Xhi, Xlo, WqTh, WqTl, nullptr, Qpre_hi, Qpre_lo);
    gemm_kernel<3, 2><<<gg, 256, 0, stream>>>(Xhi, Xlo, WkTh, WkTl, nullptr, Kpre_hi, Kpre_lo);
    rope_split2_kernel<<<32768, 256, 0, stream>>>(Qpre_hi, Qpre_lo, Qhi, Qlo,
                                                  Kpre_hi, Kpre_lo, Khi, Klo, sinT, cosT);
    gemm_kernel<1, 1><<<gg, 256, 0, stream>>>(Xhi, nullptr, WvT, nullptr, nullptr, Vt, nullptr);

    flash4_kernel<<<512, 512, 0, stream>>>(Qhi, Qlo, Khi, Klo, Vt, mask, AO);

    gemm_kernel<1, 0><<<gg, 256, 0, stream>>>(AO, nullptr, WoT, nullptr, out, nullptr, nullptr);
}

// Round 5
// 683.910 us; speedup vs baseline: 4.8727x; 1.1209x over previous
//
#include <hip/hip_runtime.h>
#include <hip/hip_bf16.h>
#include <cmath>

#define Bn 2
#define Sn 2048
#define En 2048
#define Hn 16
#define HDn 128
#define Mn (Bn*Sn)
#define NORMS2 92.33248261689366f   /* 64 * log2(e) : softmax done in base 2 */

typedef __attribute__((ext_vector_type(8))) short short8;
typedef __attribute__((ext_vector_type(4))) float f32x4;

__device__ __forceinline__ short f2bf(float x) {
    __hip_bfloat16 h = __float2bfloat16(x);
    return *reinterpret_cast<short*>(&h);
}
__device__ __forceinline__ float bf2f(short s) {
    __hip_bfloat16 h = *reinterpret_cast<__hip_bfloat16*>(&s);
    return __bfloat162float(h);
}
__device__ __forceinline__ void gl_lds16(const void* g, void* l) {
    __builtin_amdgcn_global_load_lds(
        (const __attribute__((address_space(1))) unsigned int*)g,
        (__attribute__((address_space(3))) unsigned int*)l, 16, 0, 0);
}

#if __has_builtin(__builtin_amdgcn_exp2f)
#define EXP2(x) __builtin_amdgcn_exp2f(x)
#else
#define EXP2(x) exp2f(x)
#endif

template<int CTRL>
__device__ __forceinline__ float dppf(float x) {
    int r = __builtin_amdgcn_update_dpp(0, __builtin_bit_cast(int, x), CTRL, 0xf, 0xf, true);
    return __builtin_bit_cast(float, r);
}
__device__ __forceinline__ float redmax16(float x) {
    x = fmaxf(x, dppf<0xB1>(x));   // quad_perm xor1
    x = fmaxf(x, dppf<0x4E>(x));   // quad_perm xor2
    x = fmaxf(x, dppf<0x141>(x));  // row_half_mirror xor7
    x = fmaxf(x, dppf<0x140>(x));  // row_mirror xor15
    return x;
}
__device__ __forceinline__ float redsum16(float x) {
    x += dppf<0xB1>(x);
    x += dppf<0x4E>(x);
    x += dppf<0x141>(x);
    x += dppf<0x140>(x);
    return x;
}

// ---- sin/cos tables in fp64 ----
static __global__ void rope_table_kernel(float* __restrict__ sinT, float* __restrict__ cosT) {
    int i = blockIdx.x * 256 + threadIdx.x;
    int t = i >> 6, f = i & 63;
    double inv = pow(10000.0, -(double)(2 * f) / (double)HDn);
    double ang = (double)t * inv;
    sinT[i] = (float)sin(ang);
    cosT[i] = (float)cos(ang);
}

// ---- split fp32 -> bf16 hi/lo ----
static __global__ void split_x_kernel(const float* __restrict__ X,
                                      short* __restrict__ Xhi, short* __restrict__ Xlo) {
    int i = (blockIdx.x * 256 + threadIdx.x) * 4;
    float4 x = *(const float4*)&X[i];
    short4 hi, lo;
    hi.x = f2bf(x.x); lo.x = f2bf(x.x - bf2f(hi.x));
    hi.y = f2bf(x.y); lo.y = f2bf(x.y - bf2f(hi.y));
    hi.z = f2bf(x.z); lo.z = f2bf(x.z - bf2f(hi.z));
    hi.w = f2bf(x.w); lo.w = f2bf(x.w - bf2f(hi.w));
    *(short4*)&Xhi[i] = hi;
    *(short4*)&Xlo[i] = lo;
}

// ---- mask fp32 -> bf16, pre-scaled by NORMS2 (exact for zero mask) ----
static __global__ void maskconv_kernel(const float* __restrict__ M, short* __restrict__ MB) {
    int i = (blockIdx.x * 256 + threadIdx.x) * 4;
    float4 m = *(const float4*)&M[i];
    short4 o;
    o.x = f2bf(m.x * NORMS2); o.y = f2bf(m.y * NORMS2);
    o.z = f2bf(m.z * NORMS2); o.w = f2bf(m.w * NORMS2);
    *(short4*)&MB[i] = o;
}

// ---- transpose all 4 weights in one dispatch (z selects) ----
static __global__ __launch_bounds__(256) void wtrans4_kernel(
        const float* __restrict__ Wq, const float* __restrict__ Wk,
        const float* __restrict__ Wv, const float* __restrict__ Wo,
        short* __restrict__ QKh, short* __restrict__ QKl,
        short* __restrict__ VT, short* __restrict__ OT) {
    __shared__ float tile[32][33];
    const int z = blockIdx.z;
    const float* W = (z == 0) ? Wq : (z == 1) ? Wk : (z == 2) ? Wv : Wo;
    short* Th = (z <= 1) ? QKh : (z == 2) ? VT : OT;
    const int rowoff = (z == 1) ? 2048 : 0;
    const bool split = (z <= 1);
    int tx = threadIdx.x & 31, ty = threadIdx.x >> 5;
    int k0 = blockIdx.y * 32, n0 = blockIdx.x * 32;
    #pragma unroll
    for (int i = 0; i < 4; ++i)
        tile[ty + i * 8][tx] = W[(size_t)(k0 + ty + i * 8) * En + n0 + tx];
    __syncthreads();
    #pragma unroll
    for (int i = 0; i < 4; ++i) {
        float v = tile[tx][ty + i * 8];
        size_t idx = (size_t)(rowoff + n0 + ty + i * 8) * En + k0 + tx;
        short hv = f2bf(v);
        Th[idx] = hv;
        if (split) QKl[idx] = f2bf(v - bf2f(hv));
    }
}

// ---- MFMA GEMM: C[M][N] = A[M][K] * BT[N][K]^T, 128x128 tile, BK=32 ----
// NPROD=3: split products (hi*hi + hi*lo + lo*hi)
// OUTMODE=0: fp32 row-major -> Cf
// OUTMODE=1: bf16 V^T [(b,h,d)][s] via LDS transpose (coalesced) -> Cbt
// OUTMODE=3: packed (hi<<16|lo) int32 row-major, cols<2048 -> Qpk else Kpk
template<int NPROD, int OUTMODE>
static __global__ __launch_bounds__(256) void gemm_kernel(
        const short* __restrict__ Ahi, const short* __restrict__ Alo,
        const short* __restrict__ Bhi, const short* __restrict__ Blo,
        float* __restrict__ Cf, short* __restrict__ Cbt,
        int* __restrict__ Qpk, int* __restrict__ Kpk) {
    __shared__ short As_hi[128 * 32];
    __shared__ short Bs_hi[128 * 32];
    __shared__ short As_lo[NPROD == 3 ? 128 * 32 : 8];
    __shared__ short Bs_lo[NPROD == 3 ? 128 * 32 : 8];
    __shared__ short Ts[OUTMODE == 1 ? 128 * 136 : 8];

    const int tid = threadIdx.x;
    const int w = tid >> 6, l = tid & 63;
    const int quad = l >> 4, l15 = l & 15;
    const int wr = (w >> 1) * 64, wc = (w & 1) * 64;
    const int row0 = blockIdx.y * 128, col0 = blockIdx.x * 128;

    const int off0 = tid * 16;
    const int r_a = off0 >> 6;
    const int kb = (off0 & 63) >> 1;

    f32x4 acc[4][4];
    #pragma unroll
    for (int i = 0; i < 4; ++i)
        #pragma unroll
        for (int j = 0; j < 4; ++j) acc[i][j] = f32x4{0.f, 0.f, 0.f, 0.f};

    for (int k0 = 0; k0 < En; k0 += 32) {
        const short* ap = Ahi + (size_t)(row0 + r_a) * En + k0 + kb;
        const short* bp = Bhi + (size_t)(col0 + r_a) * En + k0 + kb;
        gl_lds16(ap,           &As_hi[off0 / 2]);
        gl_lds16(ap + 64 * En, &As_hi[(off0 + 4096) / 2]);
        gl_lds16(bp,           &Bs_hi[off0 / 2]);
        gl_lds16(bp + 64 * En, &Bs_hi[(off0 + 4096) / 2]);
        if constexpr (NPROD == 3) {
            const short* ap2 = Alo + (size_t)(row0 + r_a) * En + k0 + kb;
            const short* bp2 = Blo + (size_t)(col0 + r_a) * En + k0 + kb;
            gl_lds16(ap2,           &As_lo[off0 / 2]);
            gl_lds16(ap2 + 64 * En, &As_lo[(off0 + 4096) / 2]);
            gl_lds16(bp2,           &Bs_lo[off0 / 2]);
            gl_lds16(bp2 + 64 * En, &Bs_lo[(off0 + 4096) / 2]);
        }
        __syncthreads();

        short8 bhf[4], blf[4];
        #pragma unroll
        for (int ni = 0; ni < 4; ++ni) {
            bhf[ni] = *(const short8*)&Bs_hi[(wc + ni * 16 + l15) * 32 + quad * 8];
            if constexpr (NPROD == 3)
                blf[ni] = *(const short8*)&Bs_lo[(wc + ni * 16 + l15) * 32 + quad * 8];
        }
        #pragma unroll
        for (int mi = 0; mi < 4; ++mi) {
            short8 ahf = *(const short8*)&As_hi[(wr + mi * 16 + l15) * 32 + quad * 8];
            short8 alf;
            if constexpr (NPROD == 3)
                alf = *(const short8*)&As_lo[(wr + mi * 16 + l15) * 32 + quad * 8];
            #pragma unroll
            for (int ni = 0; ni < 4; ++ni) {
                acc[mi][ni] = __builtin_amdgcn_mfma_f32_16x16x32_bf16(ahf, bhf[ni], acc[mi][ni], 0, 0, 0);
                if constexpr (NPROD == 3) {
                    acc[mi][ni] = __builtin_amdgcn_mfma_f32_16x16x32_bf16(ahf, blf[ni], acc[mi][ni], 0, 0, 0);
                    acc[mi][ni] = __builtin_amdgcn_mfma_f32_16x16x32_bf16(alf, bhf[ni], acc[mi][ni], 0, 0, 0);
                }
            }
        }
        __syncthreads();
    }

    if constexpr (OUTMODE == 0) {
        #pragma unroll
        for (int mi = 0; mi < 4; ++mi)
            #pragma unroll
            for (int ni = 0; ni < 4; ++ni) {
                int r = row0 + wr + mi * 16 + quad * 4;
                int c = col0 + wc + ni * 16 + l15;
                #pragma unroll
                for (int reg = 0; reg < 4; ++reg)
                    Cf[(size_t)(r + reg) * En + c] = acc[mi][ni][reg];
            }
    } else if constexpr (OUTMODE == 1) {
        // LDS transpose -> coalesced V^T stores
        #pragma unroll
        for (int mi = 0; mi < 4; ++mi)
            #pragma unroll
            for (int ni = 0; ni < 4; ++ni) {
                int dl = wc + ni * 16 + l15;            // local col (d)
                int sl = wr + mi * 16 + quad * 4;       // local row (s)
                #pragma unroll
                for (int reg = 0; reg < 4; ++reg)
                    Ts[dl * 136 + sl + reg] = f2bf(acc[mi][ni][reg]);
            }
        __syncthreads();
        int dl = tid >> 1, s0 = (tid & 1) * 64;
        int b = row0 >> 11, h = col0 >> 7;
        size_t gbase = ((size_t)(b * Hn + h) * HDn + dl) * Sn + (row0 & (Sn - 1)) + s0;
        #pragma unroll
        for (int k = 0; k < 8; ++k) {
            short8 vv = *(const short8*)&Ts[dl * 136 + s0 + k * 8];
            *(short8*)&Cbt[gbase + k * 8] = vv;
        }
    } else {
        int* dst = (col0 >= 2048) ? Kpk : Qpk;
        const int cb = col0 & 2047;
        #pragma unroll
        for (int mi = 0; mi < 4; ++mi)
            #pragma unroll
            for (int ni = 0; ni < 4; ++ni) {
                int r = row0 + wr + mi * 16 + quad * 4;
                int c = cb + wc + ni * 16 + l15;
                #pragma unroll
                for (int reg = 0; reg < 4; ++reg) {
                    float v = acc[mi][ni][reg];
                    short hh = f2bf(v);
                    short ll = f2bf(v - bf2f(hh));
                    dst[(size_t)(r + reg) * 2048 + c] =
                        ((int)(unsigned short)hh << 16) | (unsigned short)ll;
                }
            }
    }
}

// ---- RoPE on packed (hi<<16|lo) int32 -> split bf16 planes ----
static __global__ void rope_pk_kernel(const int* __restrict__ Pre,
        short* __restrict__ Yh, short* __restrict__ Yl,
        const float* __restrict__ sinT, const float* __restrict__ cosT) {
    int p = blockIdx.x * 256 + threadIdx.x;       // < 2^21 ; 4 elements/thread
    int u = p & 511;
    int t = (p >> 9) & (Sn - 1);
    int b = p >> 20;
    int tsrc; float sgn;
    if (t < Sn / 2) { tsrc = 2 * t + 1; sgn = -1.f; }
    else            { tsrc = 2 * (t - Sn / 2); sgn = 1.f; }
    int f0 = (2 * u) & 63, f1 = (2 * u + 1) & 63;
    float sv0 = sinT[(t << 6) + f0], cv0 = cosT[(t << 6) + f0];
    float sv1 = sinT[(t << 6) + f1], cv1 = cosT[(t << 6) + f1];
    size_t rt = ((size_t)(b * Sn + t)) * 512 + u;     // int4 units
    size_t rs = ((size_t)(b * Sn + tsrc)) * 512 + u;
    int4 xt = ((const int4*)Pre)[rt];
    int4 xs = ((const int4*)Pre)[rs];
    auto up = [](int v) -> float {
        return bf2f((short)(v >> 16)) + bf2f((short)(v & 0xffff));
    };
    float x0 = up(xt.x), x1 = up(xt.y), x2 = up(xt.z), x3 = up(xt.w);
    float s0 = up(xs.x), s1 = up(xs.y), s2 = up(xs.z), s3 = up(xs.w);
    float y0 = x0 * cv0 + sgn * s0 * sv0;
    float y1 = x1 * cv0 + sgn * s1 * sv0;
    float y2 = x2 * cv1 + sgn * s2 * sv1;
    float y3 = x3 * cv1 + sgn * s3 * sv1;
    short4 hi, lo;
    hi.x = f2bf(y0); lo.x = f2bf(y0 - bf2f(hi.x));
    hi.y = f2bf(y1); lo.y = f2bf(y1 - bf2f(hi.y));
    hi.z = f2bf(y2); lo.z = f2bf(y2 - bf2f(hi.z));
    hi.w = f2bf(y3); lo.w = f2bf(y3 - bf2f(hi.w));
    size_t o = ((size_t)(b * Sn + t)) * En + 4 * u;
    *(short4*)&Yh[o] = hi;
    *(short4*)&Yl[o] = lo;
}

// ---- MFMA flash attention v5 ----
// 512 threads (8 waves), 128 q-rows/block, 64-key tiles; bf16 pre-scaled mask.
// LDS (shorts): [0,8192)=K-hi  [8192,16384)=K-lo  [16384,24576)=V  [24576,34816)=P
static __global__ __launch_bounds__(512, 2) void flash5_kernel(
        const short* __restrict__ Qhi, const short* __restrict__ Qlo,
        const short* __restrict__ Khi, const short* __restrict__ Klo,
        const short* __restrict__ Vt, const short* __restrict__ maskB,
        short* __restrict__ AO) {
    __shared__ short lds0[34816];

    const int tid = threadIdx.x;
    const int w = tid >> 6, l = tid & 63;
    const int quad = l >> 4, l15 = l & 15;
    const int n = blockIdx.x;
    const int bh = (n & 7) * 4 + ((n >> 3) & 3);   // heads grouped per XCD
    const int qt = n >> 5;                          // 32 consecutive blocks share mask rows
    const int b = bh >> 4, h = bh & 15;
    const int r0 = qt * 128;
    const size_t qkbase = (size_t)b * Sn * En + (size_t)h * HDn;
    const int psb = 24576 + w * 1280;

    #pragma unroll
    for (int c = 0; c < 4; ++c) {
        int off = tid * 16 + c * 8192;
        int row = off >> 8;
        int gp = (off >> 4) & 15;
        int gl = gp ^ (row & 7);
        size_t gidx = qkbase + (size_t)(r0 + row) * En + gl * 8;
        gl_lds16(Qhi + gidx, &lds0[off / 2]);
        gl_lds16(Qlo + gidx, &lds0[16384 + off / 2]);
    }
    __syncthreads();
    short8 qh[4], ql[4];
    {
        int row = 16 * w + l15;
        #pragma unroll
        for (int kc = 0; kc < 4; ++kc) {
            int gp = (kc * 4 + quad) ^ (row & 7);
            qh[kc] = *(const short8*)&lds0[row * 128 + gp * 8];
            ql[kc] = *(const short8*)&lds0[16384 + row * 128 + gp * 8];
        }
    }

    f32x4 O[8];
    #pragma unroll
    for (int di = 0; di < 8; ++di) O[di] = f32x4{0.f, 0.f, 0.f, 0.f};
    float m_prev[4] = {-INFINITY, -INFINITY, -INFINITY, -INFINITY};
    float l_run[4] = {0.f, 0.f, 0.f, 0.f};
    const int qrow_base = r0 + 16 * w + quad * 4;

    for (int j0 = 0; j0 < Sn; j0 += 64) {
        __syncthreads();                       // A: prev K/V readers done
        #pragma unroll
        for (int c = 0; c < 2; ++c) {          // stage K hi/lo
            int off = tid * 16 + c * 8192;
            int row = off >> 8;
            int gp = (off >> 4) & 15;
            int gl = gp ^ (row & 7);
            size_t gidx = qkbase + (size_t)(j0 + row) * En + gl * 8;
            gl_lds16(Khi + gidx, &lds0[off / 2]);
            gl_lds16(Klo + gidx, &lds0[8192 + off / 2]);
        }
        #pragma unroll
        for (int c = 0; c < 2; ++c) {          // stage V
            int off = tid * 16 + c * 8192;
            int vrow = off >> 7;
            int vgp = (off >> 4) & 7;
            int vgl = vgp ^ (vrow & 7);
            size_t vidx = ((size_t)bh * HDn + vrow) * Sn + j0 + vgl * 8;
            gl_lds16(Vt + vidx, &lds0[16384 + off / 2]);
        }
        float mv[4][4];                        // bf16 mask prefetch (pre-scaled)
        #pragma unroll
        for (int ni = 0; ni < 4; ++ni)
            #pragma unroll
            for (int reg = 0; reg < 4; ++reg)
                mv[ni][reg] = bf2f(maskB[(size_t)(qrow_base + reg) * Sn + j0 + ni * 16 + l15]);
        __syncthreads();                       // B: K/V visible

        // ---- QK^T (3 split products) ----
        f32x4 p[4];
        #pragma unroll
        for (int ni = 0; ni < 4; ++ni) p[ni] = f32x4{0.f, 0.f, 0.f, 0.f};
        #pragma unroll
        for (int ni = 0; ni < 4; ++ni) {
            int col = ni * 16 + l15;
            #pragma unroll
            for (int kc = 0; kc < 4; ++kc) {
                int gp = (kc * 4 + quad) ^ (col & 7);
                short8 kh = *(const short8*)&lds0[col * 128 + gp * 8];
                short8 kl = *(const short8*)&lds0[8192 + col * 128 + gp * 8];
                p[ni] = __builtin_amdgcn_mfma_f32_16x16x32_bf16(qh[kc], kh, p[ni], 0, 0, 0);
                p[ni] = __builtin_amdgcn_mfma_f32_16x16x32_bf16(qh[kc], kl, p[ni], 0, 0, 0);
                p[ni] = __builtin_amdgcn_mfma_f32_16x16x32_bf16(ql[kc], kh, p[ni], 0, 0, 0);
            }
        }

        // ---- softmax in base 2, DPP reductions ----
        float rm[4] = {-INFINITY, -INFINITY, -INFINITY, -INFINITY};
        #pragma unroll
        for (int ni = 0; ni < 4; ++ni)
            #pragma unroll
            for (int reg = 0; reg < 4; ++reg) {
                float v = fmaf(p[ni][reg], NORMS2, mv[ni][reg]);
                p[ni][reg] = v;
                rm[reg] = fmaxf(rm[reg], v);
            }
        #pragma unroll
        for (int reg = 0; reg < 4; ++reg) rm[reg] = redmax16(rm[reg]);
        float al[4], mn[4], rs[4];
        #pragma unroll
        for (int reg = 0; reg < 4; ++reg) {
            mn[reg] = fmaxf(m_prev[reg], rm[reg]);
            al[reg] = EXP2(m_prev[reg] - mn[reg]);
            rs[reg] = 0.f;
        }
        #pragma unroll
        for (int ni = 0; ni < 4; ++ni)
            #pragma unroll
            for (int reg = 0; reg < 4; ++reg) {
                float pe = EXP2(p[ni][reg] - mn[reg]);
                rs[reg] += pe;
                lds0[psb + (quad * 4 + reg) * 80 + ((ni ^ quad) << 4) + l15] = f2bf(pe);
            }
        #pragma unroll
        for (int reg = 0; reg < 4; ++reg) rs[reg] = redsum16(rs[reg]);
        #pragma unroll
        for (int reg = 0; reg < 4; ++reg) {
            l_run[reg] = l_run[reg] * al[reg] + rs[reg];
            m_prev[reg] = mn[reg];
        }
        #pragma unroll
        for (int di = 0; di < 8; ++di)
            #pragma unroll
            for (int reg = 0; reg < 4; ++reg)
                O[di][reg] *= al[reg];

        short8 pa[2];
        #pragma unroll
        for (int kc2 = 0; kc2 < 2; ++kc2) {
            int g = kc2 * 2 + (quad >> 1);
            int gs = g ^ (l15 >> 2);
            pa[kc2] = *(const short8*)&lds0[psb + l15 * 80 + (gs << 4) + (quad & 1) * 8];
        }

        // ---- PV ----
        #pragma unroll
        for (int di = 0; di < 8; ++di) {
            int d = di * 16 + l15;
            #pragma unroll
            for (int kc2 = 0; kc2 < 2; ++kc2) {
                int gp = (kc2 * 4 + quad) ^ (d & 7);
                short8 vb = *(const short8*)&lds0[16384 + d * 64 + gp * 8];
                O[di] = __builtin_amdgcn_mfma_f32_16x16x32_bf16(pa[kc2], vb, O[di], 0, 0, 0);
            }
        }
    }

    float inv[4];
    #pragma unroll
    for (int reg = 0; reg < 4; ++reg) inv[reg] = 1.0f / l_run[reg];
    #pragma unroll
    for (int di = 0; di < 8; ++di)
        #pragma unroll
        for (int reg = 0; reg < 4; ++reg) {
            size_t idx = ((size_t)b * Sn + qrow_base + reg) * En + h * HDn + di * 16 + l15;
            AO[idx] = f2bf(O[di][reg] * inv[reg]);
        }
}

extern "C" void kernel_launch(void* const* d_in, const int* in_sizes, int n_in,
                              void* d_out, int out_size, void* d_ws, size_t ws_size,
                              hipStream_t stream) {
    const float* inputs = (const float*)d_in[0];
    const float* mask   = (const float*)d_in[1];
    const float* wq     = (const float*)d_in[2];
    const float* wk     = (const float*)d_in[3];
    const float* wv     = (const float*)d_in[4];
    const float* wo     = (const float*)d_in[5];
    float* out = (float*)d_out;
    (void)in_sizes; (void)n_in; (void)out_size; (void)ws_size;

    char* W8 = (char*)d_ws;
    float* sinT  = (float*)(W8 + 0);
    float* cosT  = (float*)(W8 + 524288);
    short* Xhi   = (short*)(W8 + 1048576);
    short* Xlo   = (short*)(W8 + 17825792);
    short* maskB = (short*)(W8 + 34603008);
    short* WqkTh = (short*)(W8 + 42991616);
    short* WqkTl = (short*)(W8 + 59768832);
    short* WvT   = (short*)(W8 + 76546048);
    short* WoT   = (short*)(W8 + 84934656);
    int*   Qpk   = (int*)(W8 + 93323264);
    int*   Kpk   = (int*)(W8 + 126877696);
    // aliases (lifetimes disjoint; ordering enforced by dispatch sequence):
    short* Qhi = WqkTh;                        // rope-Q out over W-qk (dead after QK-GEMM)
    short* Qlo = WqkTl;
    short* Khi = (short*)(W8 + 93323264);      // rope-K out over Qpk (dead after rope-Q)
    short* Klo = (short*)(W8 + 110100480);
    short* Vt  = (short*)(W8 + 126877696);     // V^T over Kpk (dead after rope-K)
    short* AO  = Xhi;                          // flash out over X-hi (dead after V-GEMM)

    rope_table_kernel<<<512, 256, 0, stream>>>(sinT, cosT);
    split_x_kernel<<<8192, 256, 0, stream>>>(inputs, Xhi, Xlo);
    maskconv_kernel<<<4096, 256, 0, stream>>>(mask, maskB);
    wtrans4_kernel<<<dim3(64, 64, 4), 256, 0, stream>>>(wq, wk, wv, wo,
                                                        WqkTh, WqkTl, WvT, WoT);

    gemm_kernel<3, 3><<<dim3(32, 32), 256, 0, stream>>>(
        Xhi, Xlo, WqkTh, WqkTl, nullptr, nullptr, Qpk, Kpk);
    rope_pk_kernel<<<8192, 256, 0, stream>>>(Qpk, Qhi, Qlo, sinT, cosT);
    rope_pk_kernel<<<8192, 256, 0, stream>>>(Kpk, Khi, Klo, sinT, cosT);
    gemm_kernel<1, 1><<<dim3(16, 32), 256, 0, stream>>>(
        Xhi, nullptr, WvT, nullptr, nullptr, Vt, nullptr, nullptr);

    flash5_kernel<<<512, 512, 0, stream>>>(Qhi, Qlo, Khi, Klo, Vt, maskB, AO);

    gemm_kernel<1, 0><<<dim3(16, 32), 256, 0, stream>>>(
        AO, nullptr, WoT, nullptr, out, nullptr, nullptr, nullptr);
}